// Round 1
// baseline (577.486 us; speedup 1.0000x reference)
//
#include <hip/hip_runtime.h>
#include <hip/hip_bf16.h>

// ============================================================================
// CrossNeuronBlock — round 3: fusion.
//   extract(v4) -> MLP1a -> MLP1b(+transposed store to xv1T, +row-mean atomics)
//   -> denom_k (softmax denominators from means) -> gemm_attn (A computed
//   on the fly, no At buffer, XCD swizzle) -> MLP2a -> MLP2b(+BN col stats)
//   -> bnfin -> final(v4)
// B=64 chunks, S=576, C=1024, H=72->96pad, 2 blocks of 512. All GEMMs:
// 128x128 tile, BK=32, mfma 16x16x32 bf16, global_load_lds w16, fp32 accum.
// ============================================================================

#define EPS 1e-5f

typedef __attribute__((ext_vector_type(8))) short short8;
typedef __attribute__((ext_vector_type(4))) short short4v;
typedef __attribute__((ext_vector_type(4))) float f32x4;
typedef __attribute__((ext_vector_type(4))) float float4v;

#define GLD_LDS(g, l) __builtin_amdgcn_global_load_lds( \
    (const __attribute__((address_space(1))) void*)(g), \
    (__attribute__((address_space(3))) void*)(l), 16, 0, 0)

static __device__ __forceinline__ unsigned short f2bu(float f) {
    union { __hip_bfloat16 h; unsigned short u; } cv;
    cv.h = __float2bfloat16(f);
    return cv.u;
}
static __device__ __forceinline__ float bu2f(unsigned short u) {
    union { __hip_bfloat16 h; unsigned short u; } cv;
    cv.u = u;
    return __bfloat162float(cv.h);
}

// ---- weight/bias prep: bf16 + zero-padding ---------------------------------
__global__ void prep_k(const float* __restrict__ w_in1, const float* __restrict__ b_in1,
                       const float* __restrict__ w_in2,
                       const float* __restrict__ w_out1, const float* __restrict__ b_out1,
                       const float* __restrict__ w_out2,
                       __hip_bfloat16* __restrict__ w1p, __hip_bfloat16* __restrict__ w1op,
                       __hip_bfloat16* __restrict__ w2p, __hip_bfloat16* __restrict__ w2op,
                       float* __restrict__ b1p, float* __restrict__ b1op)
{
    int i = blockIdx.x * 256 + threadIdx.x;
    if (i < 128 * 576) {
        int r = i / 576, c = i - r * 576;
        w1p[i]  = __float2bfloat16(r < 72 ? w_in1[r * 576 + c] : 0.f);
        w1op[i] = __float2bfloat16(r < 72 ? w_out1[r * 576 + c] : 0.f);
    }
    if (i < 640 * 96) {
        int r = i / 96, c = i - r * 96;
        bool ok = (r < 576) && (c < 72);
        w2p[i]  = __float2bfloat16(ok ? w_in2[r * 72 + c] : 0.f);
        w2op[i] = __float2bfloat16(ok ? w_out2[r * 72 + c] : 0.f);
    }
    if (i < 128) {
        b1p[i]  = i < 72 ? b_in1[i] : 0.f;
        b1op[i] = i < 72 ? b_out1[i] : 0.f;
    }
}

// ---- gather x -> xv0 bf16, float4 loads / short4 stores --------------------
__global__ void extract_k(const float4v* __restrict__ x4, __hip_bfloat16* __restrict__ xv)
{
    int i = blockIdx.x * 256 + threadIdx.x;          // 0 .. 9,437,183
    int s4 = i % 144;                                // 576/4 vec4 per row
    int m = i / 144;
    int c = m & 1023;
    int b = m >> 10;
    int n = b & 15, ti = b >> 4;
    int ty = (ti >> 1) * 24, tx = (ti & 1) * 24;
    int s = s4 * 4;
    int sy = s / 24, sx = s - sy * 24;
    float4v v = x4[((((n << 10) + c) * 48 + ty + sy) * 48 + tx + sx) >> 2];
    short4v pk;
    pk.x = (short)f2bu(v.x); pk.y = (short)f2bu(v.y);
    pk.z = (short)f2bu(v.z); pk.w = (short)f2bu(v.w);
    *(short4v*)(xv + (long)i * 4) = pk;
}

// ---- plain NT bf16 MFMA GEMM (m97 structure) -------------------------------
template<int HAS_BIAS, int DO_RELU>
__global__ __launch_bounds__(256) void gemm_bf16(
    const unsigned short* __restrict__ A, int lda,
    const unsigned short* __restrict__ B, int ldb,
    __hip_bfloat16* __restrict__ C, int ldc,
    int N, int K, const float* __restrict__ bias)
{
    __shared__ unsigned short As[128 * 32];
    __shared__ unsigned short Bs[128 * 32];
    const int m0 = blockIdx.y * 128, n0 = blockIdx.x * 128;
    const int t = threadIdx.x;
    const int lane = t & 63, wave = t >> 6;
    const int wr = wave >> 1, wc = wave & 1;
    const int lrow = lane & 15, kq = (lane >> 4) * 8;
    const int r0 = t >> 2, c0 = (t & 3) * 8;

    f32x4 acc[4][4];
    #pragma unroll
    for (int i = 0; i < 4; ++i)
        #pragma unroll
        for (int j = 0; j < 4; ++j)
            acc[i][j] = (f32x4){0.f, 0.f, 0.f, 0.f};

    for (int k0 = 0; k0 < K; k0 += 32) {
        GLD_LDS(A + (long)(m0 + r0) * lda + k0 + c0,      &As[t * 8]);
        GLD_LDS(A + (long)(m0 + r0 + 64) * lda + k0 + c0, &As[(t + 256) * 8]);
        GLD_LDS(B + (long)(n0 + r0) * ldb + k0 + c0,      &Bs[t * 8]);
        GLD_LDS(B + (long)(n0 + r0 + 64) * ldb + k0 + c0, &Bs[(t + 256) * 8]);
        __syncthreads();
        short8 af[4], bf[4];
        #pragma unroll
        for (int i = 0; i < 4; ++i)
            af[i] = *(const short8*)&As[(wr * 64 + i * 16 + lrow) * 32 + kq];
        #pragma unroll
        for (int j = 0; j < 4; ++j)
            bf[j] = *(const short8*)&Bs[(wc * 64 + j * 16 + lrow) * 32 + kq];
        #pragma unroll
        for (int i = 0; i < 4; ++i)
            #pragma unroll
            for (int j = 0; j < 4; ++j)
                acc[i][j] = __builtin_amdgcn_mfma_f32_16x16x32_bf16(af[i], bf[j], acc[i][j], 0, 0, 0);
        __syncthreads();
    }

    const int cr = (lane >> 4) * 4;
    #pragma unroll
    for (int j = 0; j < 4; ++j) {
        int col = n0 + wc * 64 + j * 16 + lrow;
        if (col >= N) continue;
        float bv = HAS_BIAS ? bias[col] : 0.f;
        #pragma unroll
        for (int i = 0; i < 4; ++i) {
            long rowb = (long)(m0 + wr * 64 + i * 16 + cr) * ldc;
            #pragma unroll
            for (int r = 0; r < 4; ++r) {
                float v = acc[i][j][r] + bv;
                if (DO_RELU) v = fmaxf(v, 0.f);
                C[rowb + (long)r * ldc + col] = __float2bfloat16(v);
            }
        }
    }
}

// ---- MLP1b: NT GEMM, transposed store -> xv1T + row-mean atomics -----------
// A = Hp (65536 x 96), B = w2p (640 x 96), out rows m=(b,c), cols n=s.
// Stores xv1T[(z*640 + s)*512 + c_local] (z = m0>>9), skips s>=576 cols.
// atomicAdd raw row sums (no bias; pad cols contribute exactly 0) to xm_raw.
__global__ __launch_bounds__(256) void gemm_t(
    const unsigned short* __restrict__ A, int lda,
    const unsigned short* __restrict__ B, int ldb,
    __hip_bfloat16* __restrict__ xv1T,
    int K, const float* __restrict__ bias, float* __restrict__ xm_raw)
{
    __shared__ unsigned short smem[128 * 129];       // >= As(4096)+Bs(4096)
    unsigned short* As = smem;
    unsigned short* Bs = smem + 4096;
    const int m0 = blockIdx.y * 128, n0 = blockIdx.x * 128;
    const int z = m0 >> 9, m_local = m0 & 511;
    const int t = threadIdx.x;
    const int lane = t & 63, wave = t >> 6;
    const int wr = wave >> 1, wc = wave & 1;
    const int lrow = lane & 15, kq = (lane >> 4) * 8;
    const int r0 = t >> 2, c0 = (t & 3) * 8;

    f32x4 acc[4][4];
    #pragma unroll
    for (int i = 0; i < 4; ++i)
        #pragma unroll
        for (int j = 0; j < 4; ++j)
            acc[i][j] = (f32x4){0.f, 0.f, 0.f, 0.f};

    for (int k0 = 0; k0 < K; k0 += 32) {
        GLD_LDS(A + (long)(m0 + r0) * lda + k0 + c0,      &As[t * 8]);
        GLD_LDS(A + (long)(m0 + r0 + 64) * lda + k0 + c0, &As[(t + 256) * 8]);
        GLD_LDS(B + (long)(n0 + r0) * ldb + k0 + c0,      &Bs[t * 8]);
        GLD_LDS(B + (long)(n0 + r0 + 64) * ldb + k0 + c0, &Bs[(t + 256) * 8]);
        __syncthreads();
        short8 af[4], bf[4];
        #pragma unroll
        for (int i = 0; i < 4; ++i)
            af[i] = *(const short8*)&As[(wr * 64 + i * 16 + lrow) * 32 + kq];
        #pragma unroll
        for (int j = 0; j < 4; ++j)
            bf[j] = *(const short8*)&Bs[(wc * 64 + j * 16 + lrow) * 32 + kq];
        #pragma unroll
        for (int i = 0; i < 4; ++i)
            #pragma unroll
            for (int j = 0; j < 4; ++j)
                acc[i][j] = __builtin_amdgcn_mfma_f32_16x16x32_bf16(af[i], bf[j], acc[i][j], 0, 0, 0);
        __syncthreads();
    }

    const int cr = (lane >> 4) * 4;

    // row-mean partials: sum over this block's 128 cols (pad cols are 0)
    #pragma unroll
    for (int i = 0; i < 4; ++i)
        #pragma unroll
        for (int r = 0; r < 4; ++r) {
            float v = acc[i][0][r] + acc[i][1][r] + acc[i][2][r] + acc[i][3][r];
            v += __shfl_xor(v, 1, 64);
            v += __shfl_xor(v, 2, 64);
            v += __shfl_xor(v, 4, 64);
            v += __shfl_xor(v, 8, 64);
            if (lrow == 0)
                atomicAdd(&xm_raw[m0 + wr * 64 + i * 16 + cr + r], v);
        }

    // C tile (+bias) into LDS [row_c 128][col_s 129]
    #pragma unroll
    for (int j = 0; j < 4; ++j) {
        int col = wc * 64 + j * 16 + lrow;
        float bv = (n0 + col < 576) ? bias[n0 + col] : 0.f;
        #pragma unroll
        for (int i = 0; i < 4; ++i) {
            int row = wr * 64 + i * 16 + cr;
            #pragma unroll
            for (int r = 0; r < 4; ++r)
                smem[(row + r) * 129 + col] = f2bu(acc[i][j][r] + bv);
        }
    }
    __syncthreads();

    // transposed, coalesced store: thread -> (s-row, 64 c-elements)
    int s_r = t >> 1, chalf = (t & 1) * 64;
    if (n0 + s_r < 576) {
        __hip_bfloat16* dst = xv1T + ((long)z * 640 + n0 + s_r) * 512 + m_local + chalf;
        #pragma unroll
        for (int v8 = 0; v8 < 8; ++v8) {
            short8 pk;
            #pragma unroll
            for (int e = 0; e < 8; ++e)
                pk[e] = (short)smem[(chalf + v8 * 8 + e) * 129 + s_r];
            *(short8*)(dst + v8 * 8) = pk;
        }
    }
}

// ---- denom: normalized means + softmax denominators ------------------------
__global__ void denom_k(const float* __restrict__ xm_raw, const float* __restrict__ b_in2,
                        float* __restrict__ xmn, float* __restrict__ invd)
{
    __shared__ float sx[512];
    __shared__ float red[256];
    int z = blockIdx.x;                              // (b,blk) 0..127
    int t = threadIdx.x;
    float p = 0.f;
    for (int i = t; i < 576; i += 256) p += b_in2[i];
    red[t] = p; __syncthreads();
    for (int o = 128; o; o >>= 1) { if (t < o) red[t] += red[t + o]; __syncthreads(); }
    float btot = red[0];
    for (int i = t; i < 512; i += 256) {
        float m = (xm_raw[(long)z * 512 + i] + btot) * (1.f / 576.f);
        sx[i] = m;
        xmn[(long)z * 512 + i] = m;
    }
    __syncthreads();
    #pragma unroll
    for (int dd = 0; dd < 2; ++dd) {
        int d = t + dd * 256;
        float xd = sx[d], s = 0.f;
        for (int c = 0; c < 512; ++c) { float df = sx[c] - xd; s += __expf(-df * df); }
        invd[(long)z * 512 + d] = 1.f / s;
    }
}

// ---- fused attention bmm: A computed on the fly, B = xv1T ------------------
// out2[(z*512+d), s] = sum_c At[d,c] * xv1T[z][s][c],
// At[d,c] = exp(-(xmn_c - xmn_d)^2) * invd[d].
__global__ __launch_bounds__(256) void gemm_attn(
    const unsigned short* __restrict__ Bg,
    const float* __restrict__ xmn, const float* __restrict__ invd,
    __hip_bfloat16* __restrict__ C)
{
    __shared__ unsigned short As[128 * 32];
    __shared__ unsigned short Bs[128 * 32];
    __shared__ float sxm[512];
    __shared__ float sinv[128];
    // XCD-aware swizzle: 4 m-tiles sharing a B-strip -> same XCD (ids g,g+8,..)
    int g = blockIdx.x;
    int xcd = g & 7, idx = g >> 3;
    int y = idx & 3;
    int combo = (idx >> 2) * 8 + xcd;                // 0..639
    int nx = combo % 5, z = combo / 5;
    const int m0 = y * 128, n0 = nx * 128;
    const int t = threadIdx.x;
    const int lane = t & 63, wave = t >> 6;
    const int wr = wave >> 1, wc = wave & 1;
    const int lrow = lane & 15, kq = (lane >> 4) * 8;
    const int r0 = t >> 2, c0 = (t & 3) * 8;
    const unsigned short* B = Bg + (long)z * 640 * 512;
    __hip_bfloat16* Cz = C + (long)z * 512 * 576;

    for (int i = t; i < 512; i += 256) sxm[i] = xmn[(long)z * 512 + i];
    if (t < 128) sinv[t] = invd[(long)z * 512 + m0 + t];
    __syncthreads();

    const int dA = t >> 1, cbA = (t & 1) * 16;       // A-tile compute coords
    const float xd = sxm[m0 + dA];
    const float ivd = sinv[dA];

    f32x4 acc[4][4];
    #pragma unroll
    for (int i = 0; i < 4; ++i)
        #pragma unroll
        for (int j = 0; j < 4; ++j)
            acc[i][j] = (f32x4){0.f, 0.f, 0.f, 0.f};

    for (int k0 = 0; k0 < 512; k0 += 32) {
        GLD_LDS(B + (long)(n0 + r0) * 512 + k0 + c0,      &Bs[t * 8]);
        GLD_LDS(B + (long)(n0 + r0 + 64) * 512 + k0 + c0, &Bs[(t + 256) * 8]);
        short8 pk0, pk1;
        #pragma unroll
        for (int e = 0; e < 8; ++e) {
            float d0 = sxm[k0 + cbA + e] - xd;
            pk0[e] = (short)f2bu(__expf(-d0 * d0) * ivd);
            float d1 = sxm[k0 + cbA + 8 + e] - xd;
            pk1[e] = (short)f2bu(__expf(-d1 * d1) * ivd);
        }
        *(short8*)&As[dA * 32 + cbA]     = pk0;
        *(short8*)&As[dA * 32 + cbA + 8] = pk1;
        __syncthreads();
        short8 af[4], bf[4];
        #pragma unroll
        for (int i = 0; i < 4; ++i)
            af[i] = *(const short8*)&As[(wr * 64 + i * 16 + lrow) * 32 + kq];
        #pragma unroll
        for (int j = 0; j < 4; ++j)
            bf[j] = *(const short8*)&Bs[(wc * 64 + j * 16 + lrow) * 32 + kq];
        #pragma unroll
        for (int i = 0; i < 4; ++i)
            #pragma unroll
            for (int j = 0; j < 4; ++j)
                acc[i][j] = __builtin_amdgcn_mfma_f32_16x16x32_bf16(af[i], bf[j], acc[i][j], 0, 0, 0);
        __syncthreads();
    }

    const int cr = (lane >> 4) * 4;
    #pragma unroll
    for (int j = 0; j < 4; ++j) {
        int col = n0 + wc * 64 + j * 16 + lrow;
        if (col >= 576) continue;
        #pragma unroll
        for (int i = 0; i < 4; ++i) {
            long rowb = (long)(m0 + wr * 64 + i * 16 + cr) * 576;
            #pragma unroll
            for (int r = 0; r < 4; ++r)
                Cz[rowb + (long)r * 576 + col] = __float2bfloat16(acc[i][j][r]);
        }
    }
}

// ---- MLP2b: NT GEMM + bias + BN column-stat atomics ------------------------
__global__ __launch_bounds__(256) void gemm_bn(
    const unsigned short* __restrict__ A, int lda,
    const unsigned short* __restrict__ B, int ldb,
    __hip_bfloat16* __restrict__ C, int ldc,
    int K, const float* __restrict__ bias, float* __restrict__ statsR)
{
    __shared__ unsigned short As[128 * 32];
    __shared__ unsigned short Bs[128 * 32];
    const int m0 = blockIdx.y * 128, n0 = blockIdx.x * 128;
    const int t = threadIdx.x;
    const int lane = t & 63, wave = t >> 6;
    const int wr = wave >> 1, wc = wave & 1;
    const int lrow = lane & 15, kq = (lane >> 4) * 8;
    const int r0 = t >> 2, c0 = (t & 3) * 8;

    f32x4 acc[4][4];
    #pragma unroll
    for (int i = 0; i < 4; ++i)
        #pragma unroll
        for (int j = 0; j < 4; ++j)
            acc[i][j] = (f32x4){0.f, 0.f, 0.f, 0.f};

    for (int k0 = 0; k0 < K; k0 += 32) {
        GLD_LDS(A + (long)(m0 + r0) * lda + k0 + c0,      &As[t * 8]);
        GLD_LDS(A + (long)(m0 + r0 + 64) * lda + k0 + c0, &As[(t + 256) * 8]);
        GLD_LDS(B + (long)(n0 + r0) * ldb + k0 + c0,      &Bs[t * 8]);
        GLD_LDS(B + (long)(n0 + r0 + 64) * ldb + k0 + c0, &Bs[(t + 256) * 8]);
        __syncthreads();
        short8 af[4], bf[4];
        #pragma unroll
        for (int i = 0; i < 4; ++i)
            af[i] = *(const short8*)&As[(wr * 64 + i * 16 + lrow) * 32 + kq];
        #pragma unroll
        for (int j = 0; j < 4; ++j)
            bf[j] = *(const short8*)&Bs[(wc * 64 + j * 16 + lrow) * 32 + kq];
        #pragma unroll
        for (int i = 0; i < 4; ++i)
            #pragma unroll
            for (int j = 0; j < 4; ++j)
                acc[i][j] = __builtin_amdgcn_mfma_f32_16x16x32_bf16(af[i], bf[j], acc[i][j], 0, 0, 0);
        __syncthreads();
    }

    const int cr = (lane >> 4) * 4;
    float* st = statsR + (blockIdx.y & 7) * 1152;
    #pragma unroll
    for (int j = 0; j < 4; ++j) {
        int col = n0 + wc * 64 + j * 16 + lrow;
        bool live = col < 576;
        float bv = live ? bias[col] : 0.f;
        float s1 = 0.f, s2 = 0.f;
        #pragma unroll
        for (int i = 0; i < 4; ++i) {
            long rowb = (long)(m0 + wr * 64 + i * 16 + cr) * ldc;
            #pragma unroll
            for (int r = 0; r < 4; ++r) {
                float v = acc[i][j][r] + bv;
                s1 += v; s2 += v * v;
                if (live) C[rowb + (long)r * ldc + col] = __float2bfloat16(v);
            }
        }
        s1 += __shfl_xor(s1, 16, 64); s1 += __shfl_xor(s1, 32, 64);
        s2 += __shfl_xor(s2, 16, 64); s2 += __shfl_xor(s2, 32, 64);
        if ((lane >> 4) == 0 && live) {
            atomicAdd(&st[col], s1);
            atomicAdd(&st[576 + col], s2);
        }
    }
}

// ---- fold BN stats into per-s scale/shift ----------------------------------
__global__ void bnfin_k(const float* __restrict__ statsR,
                        const float* __restrict__ gamma, const float* __restrict__ beta,
                        float* __restrict__ ab)
{
    int s = threadIdx.x;                             // 0..575
    float sum = 0.f, sq = 0.f;
    #pragma unroll
    for (int r = 0; r < 8; ++r) {
        sum += statsR[r * 1152 + s];
        sq  += statsR[r * 1152 + 576 + s];
    }
    float mu = sum * (1.f / 65536.f);
    float var = sq * (1.f / 65536.f) - mu * mu;
    float a = gamma[s] * rsqrtf(var + EPS);
    ab[s] = a;
    ab[576 + s] = beta[s] - mu * a;
}

// ---- epilogue: out = relu(x + 0.25 * (out3*a[s] + b[s])), float4 -----------
__global__ void final_k(const float4v* __restrict__ x4, const __hip_bfloat16* __restrict__ out3,
                        const float* __restrict__ ab, float4v* __restrict__ out4)
{
    int i = blockIdx.x * 256 + threadIdx.x;          // 0 .. 9,437,183
    int xx4 = i % 12; int t = i / 12;
    int y = t % 48; t /= 48;
    int c = t & 1023; int n = t >> 10;
    int xx = xx4 * 4;
    int ti = (y / 24) * 2 + (xx / 24);
    int b = ti * 16 + n;
    int s = (y % 24) * 24 + (xx % 24);
    const __hip_bfloat16* o3 = out3 + (((long)b << 10) + c) * 576 + s;
    float4v xv = x4[i];
    float4v o;
    #pragma unroll
    for (int e = 0; e < 4; ++e) {
        float v = __bfloat162float(o3[e]);
        float bn = v * ab[s + e] + ab[576 + s + e];
        float r = (e == 0 ? xv.x : e == 1 ? xv.y : e == 2 ? xv.z : xv.w) + 0.25f * bn;
        if (e == 0) o.x = fmaxf(r, 0.f);
        else if (e == 1) o.y = fmaxf(r, 0.f);
        else if (e == 2) o.z = fmaxf(r, 0.f);
        else o.w = fmaxf(r, 0.f);
    }
    out4[i] = o;
}

extern "C" void kernel_launch(void* const* d_in, const int* in_sizes, int n_in,
                              void* d_out, int out_size, void* d_ws, size_t ws_size,
                              hipStream_t stream)
{
    const float* x      = (const float*)d_in[0];
    const float* w_in1  = (const float*)d_in[1];
    const float* b_in1  = (const float*)d_in[2];
    const float* w_in2  = (const float*)d_in[3];
    const float* b_in2  = (const float*)d_in[4];
    const float* w_out1 = (const float*)d_in[5];
    const float* b_out1 = (const float*)d_in[6];
    const float* w_out2 = (const float*)d_in[7];
    const float* b_out2 = (const float*)d_in[8];
    const float* gamma  = (const float*)d_in[9];
    const float* beta   = (const float*)d_in[10];

    char* ws = (char*)d_ws;
    __hip_bfloat16* xv0    = (__hip_bfloat16*)(ws);                 // 75,497,472
    __hip_bfloat16* Hp     = (__hip_bfloat16*)(ws + 75497472L);     // 12,582,912
    __hip_bfloat16* out3   = (__hip_bfloat16*)(ws + 88080384L);     // 75,497,472
    __hip_bfloat16* xv1T   = (__hip_bfloat16*)(ws + 163577856L);    // 83,886,080
    float*          xmn    = (float*)(ws + 247463936L);             // 262,144
    float*          xm_raw = (float*)(ws + 247726080L);             // 262,144
    float*          invd   = (float*)(ws + 247988224L);             // 262,144
    float*          statsR = (float*)(ws + 248250368L);             // 36,864
    float*          ab     = (float*)(ws + 248287232L);             // 4,608
    __hip_bfloat16* w1p    = (__hip_bfloat16*)(ws + 248291840L);
    __hip_bfloat16* w1op   = (__hip_bfloat16*)(ws + 248439296L);
    __hip_bfloat16* w2p    = (__hip_bfloat16*)(ws + 248586752L);
    __hip_bfloat16* w2op   = (__hip_bfloat16*)(ws + 248709632L);
    float*          b1p    = (float*)(ws + 248832512L);
    float*          b1op   = (float*)(ws + 248833024L);
    __hip_bfloat16* out2   = xv0;                                   // reuse

    hipMemsetAsync(xm_raw, 0, 262144, stream);
    hipMemsetAsync(statsR, 0, 36864, stream);

    prep_k<<<288, 256, 0, stream>>>(w_in1, b_in1, w_in2, w_out1, b_out1, w_out2,
                                    w1p, w1op, w2p, w2op, b1p, b1op);

    extract_k<<<36864, 256, 0, stream>>>((const float4v*)x, xv0);

    // MLP1a: Hp = relu(xv0 @ w1p^T + b1p)   M=65536 N=96 K=576
    gemm_bf16<1,1><<<dim3(1, 512), 256, 0, stream>>>(
        (const unsigned short*)xv0, 576, (const unsigned short*)w1p, 576,
        Hp, 96, 96, 576, b1p);

    // MLP1b: xv1T = (Hp @ w2p^T + b_in2)^T per z, + row-mean atomics
    gemm_t<<<dim3(5, 512), 256, 0, stream>>>(
        (const unsigned short*)Hp, 96, (const unsigned short*)w2p, 96,
        xv1T, 96, b_in2, xm_raw);

    denom_k<<<128, 256, 0, stream>>>(xm_raw, b_in2, xmn, invd);

    // fused attention bmm -> out2 (reuses xv0)
    gemm_attn<<<2560, 256, 0, stream>>>(
        (const unsigned short*)xv1T, xmn, invd, out2);

    // MLP2a: Hp = relu(out2 @ w1op^T + b1op)
    gemm_bf16<1,1><<<dim3(1, 512), 256, 0, stream>>>(
        (const unsigned short*)out2, 576, (const unsigned short*)w1op, 576,
        Hp, 96, 96, 576, b1op);

    // MLP2b: out3 = Hp @ w2op^T + b_out2, + BN stat atomics
    gemm_bn<<<dim3(5, 512), 256, 0, stream>>>(
        (const unsigned short*)Hp, 96, (const unsigned short*)w2op, 96,
        out3, 576, 96, b_out2, statsR);

    bnfin_k<<<1, 576, 0, stream>>>(statsR, gamma, beta, ab);

    final_k<<<36864, 256, 0, stream>>>((const float4v*)x, out3, ab, (float4v*)d_out);
}

// Round 2
// 562.900 us; speedup vs baseline: 1.0259x; 1.0259x over previous
//
#include <hip/hip_runtime.h>
#include <hip/hip_bf16.h>

// ============================================================================
// CrossNeuronBlock — round 4: MLP-pair fusion.
//   extract(v4) -> fused_mlp<0> (MLP1a+MLP1b: H in LDS, transposed xv1T store,
//   row-mean atomics) -> denom_k -> gemm_attn -> fused_mlp<1> (MLP2a+MLP2b:
//   H in LDS, BN col stats) -> bnfin -> final(v4)
// Eliminates Hp HBM round-trip (write + 5x overfetched re-read, twice) and
// two 2560-block low-K GEMM launches.
// B=64 chunks, S=576, C=1024, H=72->96pad, 2 blocks of 512.
// GEMM core: 128x128 tile, BK=32, mfma 16x16x32 bf16, global_load_lds w16.
// ============================================================================

#define EPS 1e-5f

typedef __attribute__((ext_vector_type(8))) short short8;
typedef __attribute__((ext_vector_type(4))) short short4v;
typedef __attribute__((ext_vector_type(4))) float f32x4;
typedef __attribute__((ext_vector_type(4))) float float4v;

#define GLD_LDS(g, l) __builtin_amdgcn_global_load_lds( \
    (const __attribute__((address_space(1))) void*)(g), \
    (__attribute__((address_space(3))) void*)(l), 16, 0, 0)

static __device__ __forceinline__ unsigned short f2bu(float f) {
    union { __hip_bfloat16 h; unsigned short u; } cv;
    cv.h = __float2bfloat16(f);
    return cv.u;
}

// ---- weight/bias prep: bf16 + zero-padding ---------------------------------
__global__ void prep_k(const float* __restrict__ w_in1, const float* __restrict__ b_in1,
                       const float* __restrict__ w_in2,
                       const float* __restrict__ w_out1, const float* __restrict__ b_out1,
                       const float* __restrict__ w_out2,
                       __hip_bfloat16* __restrict__ w1p, __hip_bfloat16* __restrict__ w1op,
                       __hip_bfloat16* __restrict__ w2p, __hip_bfloat16* __restrict__ w2op,
                       float* __restrict__ b1p, float* __restrict__ b1op)
{
    int i = blockIdx.x * 256 + threadIdx.x;
    if (i < 128 * 576) {
        int r = i / 576, c = i - r * 576;
        w1p[i]  = __float2bfloat16(r < 72 ? w_in1[r * 576 + c] : 0.f);
        w1op[i] = __float2bfloat16(r < 72 ? w_out1[r * 576 + c] : 0.f);
    }
    if (i < 640 * 96) {
        int r = i / 96, c = i - r * 96;
        bool ok = (r < 576) && (c < 72);
        w2p[i]  = __float2bfloat16(ok ? w_in2[r * 72 + c] : 0.f);
        w2op[i] = __float2bfloat16(ok ? w_out2[r * 72 + c] : 0.f);
    }
    if (i < 128) {
        b1p[i]  = i < 72 ? b_in1[i] : 0.f;
        b1op[i] = i < 72 ? b_out1[i] : 0.f;
    }
}

// ---- gather x -> xv0 bf16, float4 loads / short4 stores --------------------
__global__ void extract_k(const float4v* __restrict__ x4, __hip_bfloat16* __restrict__ xv)
{
    int i = blockIdx.x * 256 + threadIdx.x;          // 0 .. 9,437,183
    int s4 = i % 144;                                // 576/4 vec4 per row
    int m = i / 144;
    int c = m & 1023;
    int b = m >> 10;
    int n = b & 15, ti = b >> 4;
    int ty = (ti >> 1) * 24, tx = (ti & 1) * 24;
    int s = s4 * 4;
    int sy = s / 24, sx = s - sy * 24;
    float4v v = x4[((((n << 10) + c) * 48 + ty + sy) * 48 + tx + sx) >> 2];
    short4v pk;
    pk.x = (short)f2bu(v.x); pk.y = (short)f2bu(v.y);
    pk.z = (short)f2bu(v.z); pk.w = (short)f2bu(v.w);
    *(short4v*)(xv + (long)i * 4) = pk;
}

// ---- fused MLP: phase1 H=relu(A@W1^T+b1) in LDS; phase2 H@W2^T+b2 ----------
// MODE 0: epilogue = transposed store to xv1T + raw row-sum atomics (MLP1).
// MODE 1: epilogue = row-major store to C + BN column-stat atomics (MLP2).
// Grid: 512 blocks x 256 thr, each owns 128 rows m (= b*1024+c).
template<int MODE>
__global__ __launch_bounds__(256) void fused_mlp(
    const unsigned short* __restrict__ A,      // [65536][576]
    const unsigned short* __restrict__ W1,     // [128][576] (rows>=72 zero)
    const float* __restrict__ b1,              // [128] (>=72 zero)
    const unsigned short* __restrict__ W2,     // [640][96] (rows>=576, cols>=72 zero)
    const float* __restrict__ b2,              // [576]
    __hip_bfloat16* __restrict__ xv1T,         // MODE0: [128][640][512]
    float* __restrict__ xm_raw,                // MODE0: [128][512]
    __hip_bfloat16* __restrict__ C,            // MODE1: [65536][576]
    float* __restrict__ statsR)                // MODE1: [8][1152]
{
    constexpr int SMEM_SH = (MODE == 0) ? 38016 : 21504;
    __shared__ __align__(16) unsigned short smem[SMEM_SH];
    unsigned short* As = smem;                 // 128*32
    unsigned short* Bs = smem + 4096;          // 128*32
    unsigned short* Hs = smem + 8192;          // 128*104 (stride 104: 16B rows, 2-way banks)
    unsigned short* T  = smem + 21504;         // MODE0: 128*129 transpose buffer

    const int m0 = blockIdx.x * 128;
    const int t = threadIdx.x;
    const int lane = t & 63, wave = t >> 6;
    const int wr = wave >> 1, wc = wave & 1;
    const int lrow = lane & 15, kq = (lane >> 4) * 8;
    const int cr = (lane >> 4) * 4;
    const int r0 = t >> 2, c0 = (t & 3) * 8;

    f32x4 acc[4][4];
    #pragma unroll
    for (int i = 0; i < 4; ++i)
        #pragma unroll
        for (int j = 0; j < 4; ++j)
            acc[i][j] = (f32x4){0.f, 0.f, 0.f, 0.f};

    // ---- phase 1: H[128][96] = relu(A[128x576] @ W1[128x576]^T + b1) ----
    for (int k0 = 0; k0 < 576; k0 += 32) {
        GLD_LDS(A + (long)(m0 + r0) * 576 + k0 + c0,      &As[t * 8]);
        GLD_LDS(A + (long)(m0 + r0 + 64) * 576 + k0 + c0, &As[(t + 256) * 8]);
        GLD_LDS(W1 + (long)r0 * 576 + k0 + c0,            &Bs[t * 8]);
        GLD_LDS(W1 + (long)(r0 + 64) * 576 + k0 + c0,     &Bs[(t + 256) * 8]);
        __syncthreads();
        short8 af[4], bf[4];
        #pragma unroll
        for (int i = 0; i < 4; ++i)
            af[i] = *(const short8*)&As[(wr * 64 + i * 16 + lrow) * 32 + kq];
        #pragma unroll
        for (int j = 0; j < 4; ++j)
            bf[j] = *(const short8*)&Bs[(wc * 64 + j * 16 + lrow) * 32 + kq];
        #pragma unroll
        for (int i = 0; i < 4; ++i)
            #pragma unroll
            for (int j = 0; j < 4; ++j)
                acc[i][j] = __builtin_amdgcn_mfma_f32_16x16x32_bf16(af[i], bf[j], acc[i][j], 0, 0, 0);
        __syncthreads();
    }

    // park H (bias+relu, bf16) in LDS; cols >= 96 never read in phase 2
    #pragma unroll
    for (int j = 0; j < 4; ++j) {
        int col = wc * 64 + j * 16 + lrow;
        if (col < 96) {
            float bv = b1[col];
            #pragma unroll
            for (int i = 0; i < 4; ++i) {
                int row = wr * 64 + i * 16 + cr;
                #pragma unroll
                for (int r = 0; r < 4; ++r)
                    Hs[(row + r) * 104 + col] = f2bu(fmaxf(acc[i][j][r] + bv, 0.f));
            }
        }
    }
    __syncthreads();

    float rsum[4][4];
    if (MODE == 0)
        #pragma unroll
        for (int i = 0; i < 4; ++i)
            #pragma unroll
            for (int r = 0; r < 4; ++r)
                rsum[i][r] = 0.f;

    const int z = m0 >> 9, m_local = m0 & 511;

    // ---- phase 2: out[128][640] = H @ W2^T + b2, 5 n-chunks of 128 ----
    for (int n0 = 0; n0 < 640; n0 += 128) {
        f32x4 a2[4][4];
        #pragma unroll
        for (int i = 0; i < 4; ++i)
            #pragma unroll
            for (int j = 0; j < 4; ++j)
                a2[i][j] = (f32x4){0.f, 0.f, 0.f, 0.f};

        for (int k0 = 0; k0 < 96; k0 += 32) {
            GLD_LDS(W2 + (long)(n0 + r0) * 96 + k0 + c0,      &Bs[t * 8]);
            GLD_LDS(W2 + (long)(n0 + r0 + 64) * 96 + k0 + c0, &Bs[(t + 256) * 8]);
            __syncthreads();
            short8 af[4], bf[4];
            #pragma unroll
            for (int i = 0; i < 4; ++i)
                af[i] = *(const short8*)&Hs[(wr * 64 + i * 16 + lrow) * 104 + k0 + kq];
            #pragma unroll
            for (int j = 0; j < 4; ++j)
                bf[j] = *(const short8*)&Bs[(wc * 64 + j * 16 + lrow) * 32 + kq];
            #pragma unroll
            for (int i = 0; i < 4; ++i)
                #pragma unroll
                for (int j = 0; j < 4; ++j)
                    a2[i][j] = __builtin_amdgcn_mfma_f32_16x16x32_bf16(af[i], bf[j], a2[i][j], 0, 0, 0);
            __syncthreads();
        }

        if (MODE == 0) {
            // raw row sums (no bias; pad cols contribute 0)
            #pragma unroll
            for (int i = 0; i < 4; ++i)
                #pragma unroll
                for (int r = 0; r < 4; ++r)
                    rsum[i][r] += a2[i][0][r] + a2[i][1][r] + a2[i][2][r] + a2[i][3][r];

            // C tile (+bias) into T [row_c 128][col_s 129]
            #pragma unroll
            for (int j = 0; j < 4; ++j) {
                int col = wc * 64 + j * 16 + lrow;
                float bv = (n0 + col < 576) ? b2[n0 + col] : 0.f;
                #pragma unroll
                for (int i = 0; i < 4; ++i) {
                    int row = wr * 64 + i * 16 + cr;
                    #pragma unroll
                    for (int r = 0; r < 4; ++r)
                        T[(row + r) * 129 + col] = f2bu(a2[i][j][r] + bv);
                }
            }
            __syncthreads();

            // transposed, coalesced store: thread -> (s-row, 64 c-elements)
            int s_r = t >> 1, chalf = (t & 1) * 64;
            if (n0 + s_r < 576) {
                __hip_bfloat16* dst = xv1T + ((long)z * 640 + n0 + s_r) * 512 + m_local + chalf;
                #pragma unroll
                for (int v8 = 0; v8 < 8; ++v8) {
                    short8 pk;
                    #pragma unroll
                    for (int e = 0; e < 8; ++e)
                        pk[e] = (short)T[(chalf + v8 * 8 + e) * 129 + s_r];
                    *(short8*)(dst + v8 * 8) = pk;
                }
            }
            __syncthreads();
        } else {
            float* st = statsR + (blockIdx.x & 7) * 1152;
            #pragma unroll
            for (int j = 0; j < 4; ++j) {
                int col = n0 + wc * 64 + j * 16 + lrow;
                bool live = col < 576;
                float bv = live ? b2[col] : 0.f;
                float s1 = 0.f, s2 = 0.f;
                #pragma unroll
                for (int i = 0; i < 4; ++i) {
                    long rowb = (long)(m0 + wr * 64 + i * 16 + cr) * 576;
                    #pragma unroll
                    for (int r = 0; r < 4; ++r) {
                        float v = a2[i][j][r] + bv;
                        s1 += v; s2 += v * v;
                        if (live) C[rowb + (long)r * 576 + col] = __float2bfloat16(v);
                    }
                }
                s1 += __shfl_xor(s1, 16, 64); s1 += __shfl_xor(s1, 32, 64);
                s2 += __shfl_xor(s2, 16, 64); s2 += __shfl_xor(s2, 32, 64);
                if ((lane >> 4) == 0 && live) {
                    atomicAdd(&st[col], s1);
                    atomicAdd(&st[576 + col], s2);
                }
            }
        }
    }

    if (MODE == 0) {
        // reduce row sums over this wave's 16 cols, atomic once per row
        #pragma unroll
        for (int i = 0; i < 4; ++i)
            #pragma unroll
            for (int r = 0; r < 4; ++r) {
                float v = rsum[i][r];
                v += __shfl_xor(v, 1, 64);
                v += __shfl_xor(v, 2, 64);
                v += __shfl_xor(v, 4, 64);
                v += __shfl_xor(v, 8, 64);
                if (lrow == 0)
                    atomicAdd(&xm_raw[m0 + wr * 64 + i * 16 + cr + r], v);
            }
    }
}

// ---- denom: normalized means + softmax denominators ------------------------
__global__ void denom_k(const float* __restrict__ xm_raw, const float* __restrict__ b_in2,
                        float* __restrict__ xmn, float* __restrict__ invd)
{
    __shared__ float sx[512];
    __shared__ float red[256];
    int z = blockIdx.x;                              // (b,blk) 0..127
    int t = threadIdx.x;
    float p = 0.f;
    for (int i = t; i < 576; i += 256) p += b_in2[i];
    red[t] = p; __syncthreads();
    for (int o = 128; o; o >>= 1) { if (t < o) red[t] += red[t + o]; __syncthreads(); }
    float btot = red[0];
    for (int i = t; i < 512; i += 256) {
        float m = (xm_raw[(long)z * 512 + i] + btot) * (1.f / 576.f);
        sx[i] = m;
        xmn[(long)z * 512 + i] = m;
    }
    __syncthreads();
    #pragma unroll
    for (int dd = 0; dd < 2; ++dd) {
        int d = t + dd * 256;
        float xd = sx[d], s = 0.f;
        for (int c = 0; c < 512; ++c) { float df = sx[c] - xd; s += __expf(-df * df); }
        invd[(long)z * 512 + d] = 1.f / s;
    }
}

// ---- fused attention bmm: A computed on the fly, B = xv1T ------------------
// out2[(z*512+d), s] = sum_c At[d,c] * xv1T[z][s][c],
// At[d,c] = exp(-(xmn_c - xmn_d)^2) * invd[d].
__global__ __launch_bounds__(256) void gemm_attn(
    const unsigned short* __restrict__ Bg,
    const float* __restrict__ xmn, const float* __restrict__ invd,
    __hip_bfloat16* __restrict__ C)
{
    __shared__ unsigned short As[128 * 32];
    __shared__ unsigned short Bs[128 * 32];
    __shared__ float sxm[512];
    __shared__ float sinv[128];
    // XCD-aware swizzle: 4 m-tiles sharing a B-strip -> same XCD (ids g,g+8,..)
    int g = blockIdx.x;
    int xcd = g & 7, idx = g >> 3;
    int y = idx & 3;
    int combo = (idx >> 2) * 8 + xcd;                // 0..639
    int nx = combo % 5, z = combo / 5;
    const int m0 = y * 128, n0 = nx * 128;
    const int t = threadIdx.x;
    const int lane = t & 63, wave = t >> 6;
    const int wr = wave >> 1, wc = wave & 1;
    const int lrow = lane & 15, kq = (lane >> 4) * 8;
    const int r0 = t >> 2, c0 = (t & 3) * 8;
    const unsigned short* B = Bg + (long)z * 640 * 512;
    __hip_bfloat16* Cz = C + (long)z * 512 * 576;

    for (int i = t; i < 512; i += 256) sxm[i] = xmn[(long)z * 512 + i];
    if (t < 128) sinv[t] = invd[(long)z * 512 + m0 + t];
    __syncthreads();

    const int dA = t >> 1, cbA = (t & 1) * 16;       // A-tile compute coords
    const float xd = sxm[m0 + dA];
    const float ivd = sinv[dA];

    f32x4 acc[4][4];
    #pragma unroll
    for (int i = 0; i < 4; ++i)
        #pragma unroll
        for (int j = 0; j < 4; ++j)
            acc[i][j] = (f32x4){0.f, 0.f, 0.f, 0.f};

    for (int k0 = 0; k0 < 512; k0 += 32) {
        GLD_LDS(B + (long)(n0 + r0) * 512 + k0 + c0,      &Bs[t * 8]);
        GLD_LDS(B + (long)(n0 + r0 + 64) * 512 + k0 + c0, &Bs[(t + 256) * 8]);
        short8 pk0, pk1;
        #pragma unroll
        for (int e = 0; e < 8; ++e) {
            float d0 = sxm[k0 + cbA + e] - xd;
            pk0[e] = (short)f2bu(__expf(-d0 * d0) * ivd);
            float d1 = sxm[k0 + cbA + 8 + e] - xd;
            pk1[e] = (short)f2bu(__expf(-d1 * d1) * ivd);
        }
        *(short8*)&As[dA * 32 + cbA]     = pk0;
        *(short8*)&As[dA * 32 + cbA + 8] = pk1;
        __syncthreads();
        short8 af[4], bf[4];
        #pragma unroll
        for (int i = 0; i < 4; ++i)
            af[i] = *(const short8*)&As[(wr * 64 + i * 16 + lrow) * 32 + kq];
        #pragma unroll
        for (int j = 0; j < 4; ++j)
            bf[j] = *(const short8*)&Bs[(wc * 64 + j * 16 + lrow) * 32 + kq];
        #pragma unroll
        for (int i = 0; i < 4; ++i)
            #pragma unroll
            for (int j = 0; j < 4; ++j)
                acc[i][j] = __builtin_amdgcn_mfma_f32_16x16x32_bf16(af[i], bf[j], acc[i][j], 0, 0, 0);
        __syncthreads();
    }

    const int cr = (lane >> 4) * 4;
    #pragma unroll
    for (int j = 0; j < 4; ++j) {
        int col = n0 + wc * 64 + j * 16 + lrow;
        if (col >= 576) continue;
        #pragma unroll
        for (int i = 0; i < 4; ++i) {
            long rowb = (long)(m0 + wr * 64 + i * 16 + cr) * 576;
            #pragma unroll
            for (int r = 0; r < 4; ++r)
                Cz[rowb + (long)r * 576 + col] = __float2bfloat16(acc[i][j][r]);
        }
    }
}

// ---- fold BN stats into per-s scale/shift ----------------------------------
__global__ void bnfin_k(const float* __restrict__ statsR,
                        const float* __restrict__ gamma, const float* __restrict__ beta,
                        float* __restrict__ ab)
{
    int s = threadIdx.x;                             // 0..575
    float sum = 0.f, sq = 0.f;
    #pragma unroll
    for (int r = 0; r < 8; ++r) {
        sum += statsR[r * 1152 + s];
        sq  += statsR[r * 1152 + 576 + s];
    }
    float mu = sum * (1.f / 65536.f);
    float var = sq * (1.f / 65536.f) - mu * mu;
    float a = gamma[s] * rsqrtf(var + EPS);
    ab[s] = a;
    ab[576 + s] = beta[s] - mu * a;
}

// ---- epilogue: out = relu(x + 0.25 * (out3*a[s] + b[s])), float4 -----------
__global__ void final_k(const float4v* __restrict__ x4, const __hip_bfloat16* __restrict__ out3,
                        const float* __restrict__ ab, float4v* __restrict__ out4)
{
    int i = blockIdx.x * 256 + threadIdx.x;          // 0 .. 9,437,183
    int xx4 = i % 12; int t = i / 12;
    int y = t % 48; t /= 48;
    int c = t & 1023; int n = t >> 10;
    int xx = xx4 * 4;
    int ti = (y / 24) * 2 + (xx / 24);
    int b = ti * 16 + n;
    int s = (y % 24) * 24 + (xx % 24);
    const __hip_bfloat16* o3 = out3 + (((long)b << 10) + c) * 576 + s;
    float4v xv = x4[i];
    float4v o;
    #pragma unroll
    for (int e = 0; e < 4; ++e) {
        float v = __bfloat162float(o3[e]);
        float bn = v * ab[s + e] + ab[576 + s + e];
        float r = (e == 0 ? xv.x : e == 1 ? xv.y : e == 2 ? xv.z : xv.w) + 0.25f * bn;
        if (e == 0) o.x = fmaxf(r, 0.f);
        else if (e == 1) o.y = fmaxf(r, 0.f);
        else if (e == 2) o.z = fmaxf(r, 0.f);
        else o.w = fmaxf(r, 0.f);
    }
    out4[i] = o;
}

extern "C" void kernel_launch(void* const* d_in, const int* in_sizes, int n_in,
                              void* d_out, int out_size, void* d_ws, size_t ws_size,
                              hipStream_t stream)
{
    const float* x      = (const float*)d_in[0];
    const float* w_in1  = (const float*)d_in[1];
    const float* b_in1  = (const float*)d_in[2];
    const float* w_in2  = (const float*)d_in[3];
    const float* b_in2  = (const float*)d_in[4];
    const float* w_out1 = (const float*)d_in[5];
    const float* b_out1 = (const float*)d_in[6];
    const float* w_out2 = (const float*)d_in[7];
    const float* b_out2 = (const float*)d_in[8];
    const float* gamma  = (const float*)d_in[9];
    const float* beta   = (const float*)d_in[10];

    char* ws = (char*)d_ws;
    __hip_bfloat16* xv0    = (__hip_bfloat16*)(ws);                 // 75,497,472
    __hip_bfloat16* out3   = (__hip_bfloat16*)(ws + 88080384L);     // 75,497,472
    __hip_bfloat16* xv1T   = (__hip_bfloat16*)(ws + 163577856L);    // 83,886,080
    float*          xmn    = (float*)(ws + 247463936L);             // 262,144
    float*          xm_raw = (float*)(ws + 247726080L);             // 262,144
    float*          invd   = (float*)(ws + 247988224L);             // 262,144
    float*          statsR = (float*)(ws + 248250368L);             // 36,864
    float*          ab     = (float*)(ws + 248287232L);             // 4,608
    __hip_bfloat16* w1p    = (__hip_bfloat16*)(ws + 248291840L);
    __hip_bfloat16* w1op   = (__hip_bfloat16*)(ws + 248439296L);
    __hip_bfloat16* w2p    = (__hip_bfloat16*)(ws + 248586752L);
    __hip_bfloat16* w2op   = (__hip_bfloat16*)(ws + 248709632L);
    float*          b1p    = (float*)(ws + 248832512L);
    float*          b1op   = (float*)(ws + 248833024L);
    __hip_bfloat16* out2   = xv0;                                   // reuse

    hipMemsetAsync(xm_raw, 0, 262144, stream);
    hipMemsetAsync(statsR, 0, 36864, stream);

    prep_k<<<288, 256, 0, stream>>>(w_in1, b_in1, w_in2, w_out1, b_out1, w_out2,
                                    w1p, w1op, w2p, w2op, b1p, b1op);

    extract_k<<<36864, 256, 0, stream>>>((const float4v*)x, xv0);

    // fused MLP1: xv1T = (relu(xv0@w1p^T+b1p)@w2p^T + b_in2)^T + row-mean atomics
    fused_mlp<0><<<512, 256, 0, stream>>>(
        (const unsigned short*)xv0, (const unsigned short*)w1p, b1p,
        (const unsigned short*)w2p, b_in2,
        xv1T, xm_raw, nullptr, nullptr);

    denom_k<<<128, 256, 0, stream>>>(xm_raw, b_in2, xmn, invd);

    // fused attention bmm -> out2 (reuses xv0)
    gemm_attn<<<2560, 256, 0, stream>>>(
        (const unsigned short*)xv1T, xmn, invd, out2);

    // fused MLP2: out3 = relu(out2@w1op^T+b1op)@w2op^T + b_out2, + BN stats
    fused_mlp<1><<<512, 256, 0, stream>>>(
        (const unsigned short*)out2, (const unsigned short*)w1op, b1op,
        (const unsigned short*)w2op, b_out2,
        nullptr, nullptr, out3, statsR);

    bnfin_k<<<1, 576, 0, stream>>>(statsR, gamma, beta, ab);

    final_k<<<36864, 256, 0, stream>>>((const float4v*)x, out3, ab, (float4v*)d_out);
}

// Round 3
// 517.151 us; speedup vs baseline: 1.1167x; 1.0885x over previous
//
#include <hip/hip_runtime.h>
#include <hip/hip_bf16.h>

// ============================================================================
// CrossNeuronBlock — round 5: algebraic reorder (attn ∘ MLP2a commute).
//   extract(v4) -> fused_mlp1G (MLP1a -> H in LDS -> MLP1b chunks in LDS ->
//     G += w_out1 @ chunk, row-mean atomics; xv1 never hits HBM)
//   -> denom_k -> fused_attn_mlp2 (H2 = relu(At@G + b) in LDS -> out3 =
//     H2@w2op^T + BN stats) -> bnfin -> final(v4)
// Eliminates out2 (151 MB traffic), xv1T (159 MB), and 50 GF of MFMA:
//   out2 = xv1@attn (38.7 GF) replaced by H2 = At@G (8.6 GF), G = 10.7 GF.
// B=64 chunks, S=576, C=1024, H=72->96pad, 2 blocks of 512.
// GEMM core: 128x128 tile, BK=32, mfma 16x16x32 bf16, global_load_lds w16.
// ============================================================================

#define EPS 1e-5f

typedef __attribute__((ext_vector_type(8))) short short8;
typedef __attribute__((ext_vector_type(4))) short short4v;
typedef __attribute__((ext_vector_type(4))) float f32x4;
typedef __attribute__((ext_vector_type(4))) float float4v;

#define GLD_LDS(g, l) __builtin_amdgcn_global_load_lds( \
    (const __attribute__((address_space(1))) void*)(g), \
    (__attribute__((address_space(3))) void*)(l), 16, 0, 0)

static __device__ __forceinline__ unsigned short f2bu(float f) {
    union { __hip_bfloat16 h; unsigned short u; } cv;
    cv.h = __float2bfloat16(f);
    return cv.u;
}

// ---- weight/bias prep: bf16 + zero-padding ---------------------------------
__global__ void prep_k(const float* __restrict__ w_in1, const float* __restrict__ b_in1,
                       const float* __restrict__ w_in2,
                       const float* __restrict__ w_out1, const float* __restrict__ b_out1,
                       const float* __restrict__ w_out2,
                       __hip_bfloat16* __restrict__ w1p, __hip_bfloat16* __restrict__ w2p,
                       __hip_bfloat16* __restrict__ w2op, __hip_bfloat16* __restrict__ w1oq,
                       float* __restrict__ b1p, float* __restrict__ b1op)
{
    int i = blockIdx.x * 256 + threadIdx.x;          // 0 .. 81919
    if (i < 128 * 576) {
        int r = i / 576, c = i - r * 576;
        w1p[i] = __float2bfloat16(r < 72 ? w_in1[r * 576 + c] : 0.f);
    }
    if (i < 640 * 96) {
        int r = i / 96, c = i - r * 96;
        bool ok = (r < 576) && (c < 72);
        w2p[i]  = __float2bfloat16(ok ? w_in2[r * 72 + c] : 0.f);
        w2op[i] = __float2bfloat16(ok ? w_out2[r * 72 + c] : 0.f);
    }
    if (i < 128 * 640) {
        int r = i / 640, c = i - r * 640;
        w1oq[i] = __float2bfloat16((r < 72 && c < 576) ? w_out1[r * 576 + c] : 0.f);
    }
    if (i < 128) {
        b1p[i]  = i < 72 ? b_in1[i] : 0.f;
        b1op[i] = i < 72 ? b_out1[i] : 0.f;
    }
}

// ---- gather x -> xv0 bf16, float4 loads / short4 stores --------------------
__global__ void extract_k(const float4v* __restrict__ x4, __hip_bfloat16* __restrict__ xv)
{
    int i = blockIdx.x * 256 + threadIdx.x;          // 0 .. 9,437,183
    int s4 = i % 144;                                // 576/4 vec4 per row
    int m = i / 144;
    int c = m & 1023;
    int b = m >> 10;
    int n = b & 15, ti = b >> 4;
    int ty = (ti >> 1) * 24, tx = (ti & 1) * 24;
    int s = s4 * 4;
    int sy = s / 24, sx = s - sy * 24;
    float4v v = x4[((((n << 10) + c) * 48 + ty + sy) * 48 + tx + sx) >> 2];
    short4v pk;
    pk.x = (short)f2bu(v.x); pk.y = (short)f2bu(v.y);
    pk.z = (short)f2bu(v.z); pk.w = (short)f2bu(v.w);
    *(short4v*)(xv + (long)i * 4) = pk;
}

// ---- fused MLP1 + G accumulation -------------------------------------------
// Per block (128 rows m = (z, c_local chunk)):
//   phase1: H[128][96] = relu(A@W1^T + b1) -> LDS Hs
//   phase2: per s-chunk n0: chunk = H@W2^T + b2 -> LDS T [c][s]
//           rsum += raw rows; G[z][h][c_chunk] += W1O[:, s-chunk] @ chunk^T
// xv1 never leaves the CU. G = w_out1 @ xv1 per z (h-rows x c-cols).
__global__ __launch_bounds__(256) void fused_mlp1G(
    const unsigned short* __restrict__ A,      // xv0 [65536][576]
    const unsigned short* __restrict__ W1,     // w1p [128][576]
    const float* __restrict__ b1,              // b1p [128]
    const unsigned short* __restrict__ W2,     // w2p [640][96]
    const float* __restrict__ b2,              // b_in2 [576]
    const unsigned short* __restrict__ W1O,    // w1oq [128][640]
    unsigned short* __restrict__ G,            // [128 z][128 h][512 c]
    float* __restrict__ xm_raw)                // [128][512]
{
    __shared__ __align__(16) unsigned short smem[4096 + 4096 + 13312 + 17408];
    unsigned short* As = smem;                 // [128][32]
    unsigned short* Bs = smem + 4096;          // [128][32]
    unsigned short* Hs = smem + 8192;          // [128][104]
    unsigned short* T  = smem + 21504;         // [128 c][136 s] (16B-aligned rows)

    const int m0 = blockIdx.x * 128;
    const int t = threadIdx.x;
    const int lane = t & 63, wave = t >> 6;
    const int wr = wave >> 1, wc = wave & 1;
    const int lrow = lane & 15, kq = (lane >> 4) * 8;
    const int cr = (lane >> 4) * 4;
    const int r0 = t >> 2, c0 = (t & 3) * 8;

    f32x4 acc[4][4];
    #pragma unroll
    for (int i = 0; i < 4; ++i)
        #pragma unroll
        for (int j = 0; j < 4; ++j)
            acc[i][j] = (f32x4){0.f, 0.f, 0.f, 0.f};

    // ---- phase 1: H = relu(A[128x576] @ W1^T + b1) ----
    for (int k0 = 0; k0 < 576; k0 += 32) {
        GLD_LDS(A + (long)(m0 + r0) * 576 + k0 + c0,      &As[t * 8]);
        GLD_LDS(A + (long)(m0 + r0 + 64) * 576 + k0 + c0, &As[(t + 256) * 8]);
        GLD_LDS(W1 + (long)r0 * 576 + k0 + c0,            &Bs[t * 8]);
        GLD_LDS(W1 + (long)(r0 + 64) * 576 + k0 + c0,     &Bs[(t + 256) * 8]);
        __syncthreads();
        short8 af[4], bf[4];
        #pragma unroll
        for (int i = 0; i < 4; ++i)
            af[i] = *(const short8*)&As[(wr * 64 + i * 16 + lrow) * 32 + kq];
        #pragma unroll
        for (int j = 0; j < 4; ++j)
            bf[j] = *(const short8*)&Bs[(wc * 64 + j * 16 + lrow) * 32 + kq];
        #pragma unroll
        for (int i = 0; i < 4; ++i)
            #pragma unroll
            for (int j = 0; j < 4; ++j)
                acc[i][j] = __builtin_amdgcn_mfma_f32_16x16x32_bf16(af[i], bf[j], acc[i][j], 0, 0, 0);
        __syncthreads();
    }

    // park H (bias+relu, bf16) in LDS
    #pragma unroll
    for (int j = 0; j < 4; ++j) {
        int col = wc * 64 + j * 16 + lrow;
        if (col < 96) {
            float bv = b1[col];
            #pragma unroll
            for (int i = 0; i < 4; ++i) {
                int row = wr * 64 + i * 16 + cr;
                #pragma unroll
                for (int r = 0; r < 4; ++r)
                    Hs[(row + r) * 104 + col] = f2bu(fmaxf(acc[i][j][r] + bv, 0.f));
            }
        }
    }
    __syncthreads();

    float rsum[4][4];
    #pragma unroll
    for (int i = 0; i < 4; ++i)
        #pragma unroll
        for (int r = 0; r < 4; ++r)
            rsum[i][r] = 0.f;

    f32x4 gacc[4][4];
    #pragma unroll
    for (int i = 0; i < 4; ++i)
        #pragma unroll
        for (int j = 0; j < 4; ++j)
            gacc[i][j] = (f32x4){0.f, 0.f, 0.f, 0.f};

    const int z = m0 >> 9, m_local = m0 & 511;

    // ---- phase 2: 5 s-chunks of 128 ----
    for (int n0 = 0; n0 < 640; n0 += 128) {
        f32x4 a2[4][4];
        #pragma unroll
        for (int i = 0; i < 4; ++i)
            #pragma unroll
            for (int j = 0; j < 4; ++j)
                a2[i][j] = (f32x4){0.f, 0.f, 0.f, 0.f};

        for (int k0 = 0; k0 < 96; k0 += 32) {
            GLD_LDS(W2 + (long)(n0 + r0) * 96 + k0 + c0,      &Bs[t * 8]);
            GLD_LDS(W2 + (long)(n0 + r0 + 64) * 96 + k0 + c0, &Bs[(t + 256) * 8]);
            __syncthreads();
            short8 af[4], bf[4];
            #pragma unroll
            for (int i = 0; i < 4; ++i)
                af[i] = *(const short8*)&Hs[(wr * 64 + i * 16 + lrow) * 104 + k0 + kq];
            #pragma unroll
            for (int j = 0; j < 4; ++j)
                bf[j] = *(const short8*)&Bs[(wc * 64 + j * 16 + lrow) * 32 + kq];
            #pragma unroll
            for (int i = 0; i < 4; ++i)
                #pragma unroll
                for (int j = 0; j < 4; ++j)
                    a2[i][j] = __builtin_amdgcn_mfma_f32_16x16x32_bf16(af[i], bf[j], a2[i][j], 0, 0, 0);
            __syncthreads();
        }

        // raw row sums (bias handled in denom_k; pad s cols contribute 0)
        #pragma unroll
        for (int i = 0; i < 4; ++i)
            #pragma unroll
            for (int r = 0; r < 4; ++r)
                rsum[i][r] += a2[i][0][r] + a2[i][1][r] + a2[i][2][r] + a2[i][3][r];

        // chunk (+bias) -> T [c 128][s 136]; pad s cols are exactly 0+0
        #pragma unroll
        for (int j = 0; j < 4; ++j) {
            int col = wc * 64 + j * 16 + lrow;
            float bv = (n0 + col < 576) ? b2[n0 + col] : 0.f;
            #pragma unroll
            for (int i = 0; i < 4; ++i) {
                int row = wr * 64 + i * 16 + cr;
                #pragma unroll
                for (int r = 0; r < 4; ++r)
                    T[(row + r) * 136 + col] = f2bu(a2[i][j][r] + bv);
            }
        }
        __syncthreads();

        // G += W1O[:, s-chunk] @ chunk^T   (m=h from As, n=c from T)
        for (int kk = 0; kk < 128; kk += 32) {
            GLD_LDS(W1O + (long)r0 * 640 + n0 + kk + c0,        &As[t * 8]);
            GLD_LDS(W1O + (long)(r0 + 64) * 640 + n0 + kk + c0, &As[(t + 256) * 8]);
            __syncthreads();
            short8 af[4], bf[4];
            #pragma unroll
            for (int i = 0; i < 4; ++i)
                af[i] = *(const short8*)&As[(wr * 64 + i * 16 + lrow) * 32 + kq];
            #pragma unroll
            for (int j = 0; j < 4; ++j)
                bf[j] = *(const short8*)&T[(wc * 64 + j * 16 + lrow) * 136 + kk + kq];
            #pragma unroll
            for (int i = 0; i < 4; ++i)
                #pragma unroll
                for (int j = 0; j < 4; ++j)
                    gacc[i][j] = __builtin_amdgcn_mfma_f32_16x16x32_bf16(af[i], bf[j], gacc[i][j], 0, 0, 0);
            __syncthreads();
        }
    }

    // row-sum atomics (mean finished in denom_k)
    #pragma unroll
    for (int i = 0; i < 4; ++i)
        #pragma unroll
        for (int r = 0; r < 4; ++r) {
            float v = rsum[i][r];
            v += __shfl_xor(v, 1, 64);
            v += __shfl_xor(v, 2, 64);
            v += __shfl_xor(v, 4, 64);
            v += __shfl_xor(v, 8, 64);
            if (lrow == 0)
                atomicAdd(&xm_raw[m0 + wr * 64 + i * 16 + cr + r], v);
        }

    // store G chunk: rows h (0..127), cols c (m_local..m_local+127)
    unsigned short* Gz = G + (long)z * 128 * 512;
    #pragma unroll
    for (int j = 0; j < 4; ++j) {
        int cn = wc * 64 + j * 16 + lrow;
        #pragma unroll
        for (int i = 0; i < 4; ++i) {
            int h = wr * 64 + i * 16 + cr;
            #pragma unroll
            for (int r = 0; r < 4; ++r)
                Gz[(long)(h + r) * 512 + m_local + cn] = f2bu(gacc[i][j][r]);
        }
    }
}

// ---- denom: normalized means + softmax denominators ------------------------
__global__ void denom_k(const float* __restrict__ xm_raw, const float* __restrict__ b_in2,
                        float* __restrict__ xmn, float* __restrict__ invd)
{
    __shared__ float sx[512];
    __shared__ float red[256];
    int z = blockIdx.x;                              // (b,blk) 0..127
    int t = threadIdx.x;
    float p = 0.f;
    for (int i = t; i < 576; i += 256) p += b_in2[i];
    red[t] = p; __syncthreads();
    for (int o = 128; o; o >>= 1) { if (t < o) red[t] += red[t + o]; __syncthreads(); }
    float btot = red[0];
    for (int i = t; i < 512; i += 256) {
        float m = (xm_raw[(long)z * 512 + i] + btot) * (1.f / 576.f);
        sx[i] = m;
        xmn[(long)z * 512 + i] = m;
    }
    __syncthreads();
    #pragma unroll
    for (int dd = 0; dd < 2; ++dd) {
        int d = t + dd * 256;
        float xd = sx[d], s = 0.f;
        for (int c = 0; c < 512; ++c) { float df = sx[c] - xd; s += __expf(-df * df); }
        invd[(long)z * 512 + d] = 1.f / s;
    }
}

// ---- fused attention + MLP2 ------------------------------------------------
// Per block (z, d-tile of 128):
//   phase1: H2[128 d][96 h] = relu(At @ G[z] + b1op) -> LDS Hs
//           At[d,c] = exp(-(xmn_c-xmn_d)^2)*invd[d], built on the fly.
//   phase2: out3[(z,d)][s] = H2 @ w2op^T + b_out2, + BN column stats.
__global__ __launch_bounds__(256) void fused_attn_mlp2(
    const unsigned short* __restrict__ G,      // [128][128][512]
    const float* __restrict__ xmn, const float* __restrict__ invd,
    const float* __restrict__ b1,              // b1op [128]
    const unsigned short* __restrict__ W2,     // w2op [640][96]
    const float* __restrict__ b2,              // b_out2 [576]
    __hip_bfloat16* __restrict__ C,            // out3 [65536][576]
    float* __restrict__ statsR)                // [8][1152]
{
    __shared__ __align__(16) unsigned short smem[4096 + 4096 + 13312];
    unsigned short* As = smem;                 // [128][32] At tile
    unsigned short* Bs = smem + 4096;          // [128][32]
    unsigned short* Hs = smem + 8192;          // [128 d][104 h]
    __shared__ float sxm[512];
    __shared__ float sinv[128];

    // XCD swizzle: 4 d-tiles of one z -> same XCD (512 % 8 == 0, bijective)
    int bid = blockIdx.x;
    int lb = (bid & 7) * 64 + (bid >> 3);
    int z = lb >> 2;
    const int m0 = (lb & 3) * 128;
    const int t = threadIdx.x;
    const int lane = t & 63, wave = t >> 6;
    const int wr = wave >> 1, wc = wave & 1;
    const int lrow = lane & 15, kq = (lane >> 4) * 8;
    const int cr = (lane >> 4) * 4;
    const int r0 = t >> 2, c0 = (t & 3) * 8;
    const unsigned short* Gz = G + (long)z * 128 * 512;

    for (int i = t; i < 512; i += 256) sxm[i] = xmn[(long)z * 512 + i];
    if (t < 128) sinv[t] = invd[(long)z * 512 + m0 + t];
    __syncthreads();

    const int dA = t >> 1, cbA = (t & 1) * 16;
    const float xd = sxm[m0 + dA];
    const float ivd = sinv[dA];

    f32x4 acc[4][4];
    #pragma unroll
    for (int i = 0; i < 4; ++i)
        #pragma unroll
        for (int j = 0; j < 4; ++j)
            acc[i][j] = (f32x4){0.f, 0.f, 0.f, 0.f};

    // ---- phase 1: H2 = At @ G^T  (m=d, n=h, k=c) ----
    for (int k0 = 0; k0 < 512; k0 += 32) {
        GLD_LDS(Gz + (long)r0 * 512 + k0 + c0,        &Bs[t * 8]);
        GLD_LDS(Gz + (long)(r0 + 64) * 512 + k0 + c0, &Bs[(t + 256) * 8]);
        short8 pk0, pk1;
        #pragma unroll
        for (int e = 0; e < 8; ++e) {
            float d0 = sxm[k0 + cbA + e] - xd;
            pk0[e] = (short)f2bu(__expf(-d0 * d0) * ivd);
            float d1 = sxm[k0 + cbA + 8 + e] - xd;
            pk1[e] = (short)f2bu(__expf(-d1 * d1) * ivd);
        }
        *(short8*)&As[dA * 32 + cbA]     = pk0;
        *(short8*)&As[dA * 32 + cbA + 8] = pk1;
        __syncthreads();
        short8 af[4], bf[4];
        #pragma unroll
        for (int i = 0; i < 4; ++i)
            af[i] = *(const short8*)&As[(wr * 64 + i * 16 + lrow) * 32 + kq];
        #pragma unroll
        for (int j = 0; j < 4; ++j)
            bf[j] = *(const short8*)&Bs[(wc * 64 + j * 16 + lrow) * 32 + kq];
        #pragma unroll
        for (int i = 0; i < 4; ++i)
            #pragma unroll
            for (int j = 0; j < 4; ++j)
                acc[i][j] = __builtin_amdgcn_mfma_f32_16x16x32_bf16(af[i], bf[j], acc[i][j], 0, 0, 0);
        __syncthreads();
    }

    // park H2 = relu(acc + b1[h]) in Hs [d][104]
    #pragma unroll
    for (int j = 0; j < 4; ++j) {
        int col = wc * 64 + j * 16 + lrow;
        if (col < 96) {
            float bv = b1[col];
            #pragma unroll
            for (int i = 0; i < 4; ++i) {
                int row = wr * 64 + i * 16 + cr;
                #pragma unroll
                for (int r = 0; r < 4; ++r)
                    Hs[(row + r) * 104 + col] = f2bu(fmaxf(acc[i][j][r] + bv, 0.f));
            }
        }
    }
    __syncthreads();

    // ---- phase 2: out3 = H2 @ w2op^T + b2, BN stats ----
    const long mg = (long)z * 512 + m0;
    float* st = statsR + (bid & 7) * 1152;
    for (int n0 = 0; n0 < 640; n0 += 128) {
        f32x4 a2[4][4];
        #pragma unroll
        for (int i = 0; i < 4; ++i)
            #pragma unroll
            for (int j = 0; j < 4; ++j)
                a2[i][j] = (f32x4){0.f, 0.f, 0.f, 0.f};

        for (int k0 = 0; k0 < 96; k0 += 32) {
            GLD_LDS(W2 + (long)(n0 + r0) * 96 + k0 + c0,      &Bs[t * 8]);
            GLD_LDS(W2 + (long)(n0 + r0 + 64) * 96 + k0 + c0, &Bs[(t + 256) * 8]);
            __syncthreads();
            short8 af[4], bf[4];
            #pragma unroll
            for (int i = 0; i < 4; ++i)
                af[i] = *(const short8*)&Hs[(wr * 64 + i * 16 + lrow) * 104 + k0 + kq];
            #pragma unroll
            for (int j = 0; j < 4; ++j)
                bf[j] = *(const short8*)&Bs[(wc * 64 + j * 16 + lrow) * 32 + kq];
            #pragma unroll
            for (int i = 0; i < 4; ++i)
                #pragma unroll
                for (int j = 0; j < 4; ++j)
                    a2[i][j] = __builtin_amdgcn_mfma_f32_16x16x32_bf16(af[i], bf[j], a2[i][j], 0, 0, 0);
            __syncthreads();
        }

        #pragma unroll
        for (int j = 0; j < 4; ++j) {
            int col = n0 + wc * 64 + j * 16 + lrow;
            bool live = col < 576;
            float bv = live ? b2[col] : 0.f;
            float s1 = 0.f, s2 = 0.f;
            #pragma unroll
            for (int i = 0; i < 4; ++i) {
                long rowb = (mg + wr * 64 + i * 16 + cr) * 576;
                #pragma unroll
                for (int r = 0; r < 4; ++r) {
                    float v = a2[i][j][r] + bv;
                    s1 += v; s2 += v * v;
                    if (live) C[rowb + (long)r * 576 + col] = __float2bfloat16(v);
                }
            }
            s1 += __shfl_xor(s1, 16, 64); s1 += __shfl_xor(s1, 32, 64);
            s2 += __shfl_xor(s2, 16, 64); s2 += __shfl_xor(s2, 32, 64);
            if ((lane >> 4) == 0 && live) {
                atomicAdd(&st[col], s1);
                atomicAdd(&st[576 + col], s2);
            }
        }
    }
}

// ---- fold BN stats into per-s scale/shift ----------------------------------
__global__ void bnfin_k(const float* __restrict__ statsR,
                        const float* __restrict__ gamma, const float* __restrict__ beta,
                        float* __restrict__ ab)
{
    int s = threadIdx.x;                             // 0..575
    float sum = 0.f, sq = 0.f;
    #pragma unroll
    for (int r = 0; r < 8; ++r) {
        sum += statsR[r * 1152 + s];
        sq  += statsR[r * 1152 + 576 + s];
    }
    float mu = sum * (1.f / 65536.f);
    float var = sq * (1.f / 65536.f) - mu * mu;
    float a = gamma[s] * rsqrtf(var + EPS);
    ab[s] = a;
    ab[576 + s] = beta[s] - mu * a;
}

// ---- epilogue: out = relu(x + 0.25 * (out3*a[s] + b[s])), float4 -----------
__global__ void final_k(const float4v* __restrict__ x4, const __hip_bfloat16* __restrict__ out3,
                        const float* __restrict__ ab, float4v* __restrict__ out4)
{
    int i = blockIdx.x * 256 + threadIdx.x;          // 0 .. 9,437,183
    int xx4 = i % 12; int t = i / 12;
    int y = t % 48; t /= 48;
    int c = t & 1023; int n = t >> 10;
    int xx = xx4 * 4;
    int ti = (y / 24) * 2 + (xx / 24);
    int b = ti * 16 + n;
    int s = (y % 24) * 24 + (xx % 24);
    const __hip_bfloat16* o3 = out3 + (((long)b << 10) + c) * 576 + s;
    float4v xv = x4[i];
    float4v o;
    #pragma unroll
    for (int e = 0; e < 4; ++e) {
        float v = __bfloat162float(o3[e]);
        float bn = v * ab[s + e] + ab[576 + s + e];
        float r = (e == 0 ? xv.x : e == 1 ? xv.y : e == 2 ? xv.z : xv.w) + 0.25f * bn;
        if (e == 0) o.x = fmaxf(r, 0.f);
        else if (e == 1) o.y = fmaxf(r, 0.f);
        else if (e == 2) o.z = fmaxf(r, 0.f);
        else o.w = fmaxf(r, 0.f);
    }
    out4[i] = o;
}

extern "C" void kernel_launch(void* const* d_in, const int* in_sizes, int n_in,
                              void* d_out, int out_size, void* d_ws, size_t ws_size,
                              hipStream_t stream)
{
    const float* x      = (const float*)d_in[0];
    const float* w_in1  = (const float*)d_in[1];
    const float* b_in1  = (const float*)d_in[2];
    const float* w_in2  = (const float*)d_in[3];
    const float* b_in2  = (const float*)d_in[4];
    const float* w_out1 = (const float*)d_in[5];
    const float* b_out1 = (const float*)d_in[6];
    const float* w_out2 = (const float*)d_in[7];
    const float* b_out2 = (const float*)d_in[8];
    const float* gamma  = (const float*)d_in[9];
    const float* beta   = (const float*)d_in[10];

    char* ws = (char*)d_ws;
    __hip_bfloat16* xv0    = (__hip_bfloat16*)(ws);                 // 75,497,472
    __hip_bfloat16* out3   = (__hip_bfloat16*)(ws + 75497472L);     // 75,497,472
    unsigned short* G      = (unsigned short*)(ws + 150994944L);    // 16,777,216
    float*          xmn    = (float*)(ws + 167772160L);             // 262,144
    float*          xm_raw = (float*)(ws + 168034304L);             // 262,144
    float*          invd   = (float*)(ws + 168296448L);             // 262,144
    float*          statsR = (float*)(ws + 168558592L);             // 36,864
    float*          ab     = (float*)(ws + 168595456L);             // 4,608
    __hip_bfloat16* w1p    = (__hip_bfloat16*)(ws + 168600064L);    // 147,456
    __hip_bfloat16* w2p    = (__hip_bfloat16*)(ws + 168747520L);    // 122,880
    __hip_bfloat16* w2op   = (__hip_bfloat16*)(ws + 168870400L);    // 122,880
    __hip_bfloat16* w1oq   = (__hip_bfloat16*)(ws + 168993280L);    // 163,840
    float*          b1p    = (float*)(ws + 169157120L);
    float*          b1op   = (float*)(ws + 169157632L);

    hipMemsetAsync(xm_raw, 0, 262144, stream);
    hipMemsetAsync(statsR, 0, 36864, stream);

    prep_k<<<320, 256, 0, stream>>>(w_in1, b_in1, w_in2, w_out1, b_out1, w_out2,
                                    w1p, w2p, w2op, w1oq, b1p, b1op);

    extract_k<<<36864, 256, 0, stream>>>((const float4v*)x, xv0);

    // fused MLP1 + G: G[z] = w_out1 @ xv1[z], xv1 kept on-chip; row-sum atomics
    fused_mlp1G<<<512, 256, 0, stream>>>(
        (const unsigned short*)xv0, (const unsigned short*)w1p, b1p,
        (const unsigned short*)w2p, b_in2, (const unsigned short*)w1oq,
        G, xm_raw);

    denom_k<<<128, 256, 0, stream>>>(xm_raw, b_in2, xmn, invd);

    // fused attention + MLP2: H2 = relu(At@G + b1op), out3 = H2@w2op^T + BN stats
    fused_attn_mlp2<<<512, 256, 0, stream>>>(
        G, xmn, invd, b1op, (const unsigned short*)w2op, b_out2,
        out3, statsR);

    bnfin_k<<<1, 576, 0, stream>>>(statsR, gamma, beta, ab);

    final_k<<<36864, 256, 0, stream>>>((const float4v*)x, out3, ab, (float4v*)d_out);
}

// Round 4
// 484.726 us; speedup vs baseline: 1.1914x; 1.0669x over previous
//
#include <hip/hip_runtime.h>
#include <hip/hip_bf16.h>

// ============================================================================
// CrossNeuronBlock — round 6: second algebraic collapse.
//   G = w_out1 @ xv1 = (w_out1@w_in2) @ Hrelu + cG  →  xv1 never exists.
//   M = w_out1@w_in2 (72x72, f32 in prepM, bf16 once); row 72 of M = colsum(w_in2)
//   so G row 72 = raw row-sums (xm) for free; cG folds into b1G = b_out1 + cG
//   (softmax cols sum to 1). Pipeline:
//   extract(v4) -> fused_mlp1 (H=relu(A@W1^T+b1) in LDS; G-chunk = Mp@H^T;
//     xm written f32 from row-72 fragment) -> denom_k -> fused_attn_mlp2
//     (H2=relu(At@G^T+b1G) in LDS; out3=H2@w2op^T + BN stats) -> bnfin -> final.
// GEMM core: 128x128 tile, BK=32, mfma 16x16x32 bf16, global_load_lds w16.
// ============================================================================

#define EPS 1e-5f

typedef __attribute__((ext_vector_type(8))) short short8;
typedef __attribute__((ext_vector_type(4))) short short4v;
typedef __attribute__((ext_vector_type(4))) float f32x4;
typedef __attribute__((ext_vector_type(4))) float float4v;

#define GLD_LDS(g, l) __builtin_amdgcn_global_load_lds( \
    (const __attribute__((address_space(1))) void*)(g), \
    (__attribute__((address_space(3))) void*)(l), 16, 0, 0)

static __device__ __forceinline__ unsigned short f2bu(float f) {
    union { __hip_bfloat16 h; unsigned short u; } cv;
    cv.h = __float2bfloat16(f);
    return cv.u;
}

// ---- weight/bias prep: bf16 + zero-padding ---------------------------------
__global__ void prep_k(const float* __restrict__ w_in1, const float* __restrict__ b_in1,
                       const float* __restrict__ w_in2, const float* __restrict__ w_out2,
                       __hip_bfloat16* __restrict__ w1p, __hip_bfloat16* __restrict__ w2op,
                       float* __restrict__ b1p)
{
    int i = blockIdx.x * 256 + threadIdx.x;          // 0 .. 73727
    if (i < 128 * 576) {
        int r = i / 576, c = i - r * 576;
        w1p[i] = __float2bfloat16(r < 72 ? w_in1[r * 576 + c] : 0.f);
    }
    if (i < 640 * 96) {
        int r = i / 96, c = i - r * 96;
        bool ok = (r < 576) && (c < 72);
        w2op[i] = __float2bfloat16(ok ? w_out2[r * 72 + c] : 0.f);
    }
    if (i < 128)
        b1p[i] = i < 72 ? b_in1[i] : 0.f;
}

// ---- prepM: Mp = w_out1 @ w_in2 (f32 accum, bf16 once); row 72 = colsum(w_in2);
//      b1G[h] = b_out1[h] + w_out1[h,:] @ b_in2 ---------------------------------
__global__ void prepM_k(const float* __restrict__ w_out1, const float* __restrict__ w_in2,
                        const float* __restrict__ b_in2, const float* __restrict__ b_out1,
                        __hip_bfloat16* __restrict__ Mp, float* __restrict__ b1G)
{
    int i = blockIdx.x * 256 + threadIdx.x;          // 0 .. 12287
    if (i >= 128 * 96) return;
    int h = i / 96, k = i - h * 96;
    float m = 0.f;
    if (h < 72 && k < 72) {
        for (int s = 0; s < 576; ++s)
            m += w_out1[h * 576 + s] * w_in2[s * 72 + k];
    } else if (h == 72 && k < 72) {
        for (int s = 0; s < 576; ++s)
            m += w_in2[s * 72 + k];
    }
    Mp[i] = __float2bfloat16(m);
    if (k == 0) {
        float c = 0.f;
        if (h < 72)
            for (int s = 0; s < 576; ++s)
                c += w_out1[h * 576 + s] * b_in2[s];
        b1G[h] = (h < 72) ? b_out1[h] + c : 0.f;
    }
}

// ---- gather x -> xv0 bf16, float4 loads / short4 stores --------------------
__global__ void extract_k(const float4v* __restrict__ x4, __hip_bfloat16* __restrict__ xv)
{
    int i = blockIdx.x * 256 + threadIdx.x;          // 0 .. 9,437,183
    int s4 = i % 144;                                // 576/4 vec4 per row
    int m = i / 144;
    int c = m & 1023;
    int b = m >> 10;
    int n = b & 15, ti = b >> 4;
    int ty = (ti >> 1) * 24, tx = (ti & 1) * 24;
    int s = s4 * 4;
    int sy = s / 24, sx = s - sy * 24;
    float4v v = x4[((((n << 10) + c) * 48 + ty + sy) * 48 + tx + sx) >> 2];
    short4v pk;
    pk.x = (short)f2bu(v.x); pk.y = (short)f2bu(v.y);
    pk.z = (short)f2bu(v.z); pk.w = (short)f2bu(v.w);
    *(short4v*)(xv + (long)i * 4) = pk;
}

// ---- fused MLP1 -> G -------------------------------------------------------
// Per block (128 rows m = (z, c_local chunk)):
//   phase1: H[128 c][96 k] = relu(A@W1^T + b1) -> LDS Hs
//   phase2: G-chunk[128 h][128 c] = Mp @ H^T  (K=96, 3 K-steps)
//   row 72 of chunk = raw xm row-sums -> written f32 to xm_raw (exclusive).
__global__ __launch_bounds__(256) void fused_mlp1(
    const unsigned short* __restrict__ A,      // xv0 [65536][576]
    const unsigned short* __restrict__ W1,     // w1p [128][576]
    const float* __restrict__ b1,              // b1p [128]
    const unsigned short* __restrict__ Mp,     // [128][96]
    unsigned short* __restrict__ G,            // [128 z][128 h][512 c]
    float* __restrict__ xm_raw)                // [128][512]
{
    __shared__ __align__(16) unsigned short smem[4096 + 4096 + 13312];
    unsigned short* As = smem;                 // [128][32]
    unsigned short* Bs = smem + 4096;          // [128][32]
    unsigned short* Hs = smem + 8192;          // [128 c][104 k]

    const int m0 = blockIdx.x * 128;
    const int t = threadIdx.x;
    const int lane = t & 63, wave = t >> 6;
    const int wr = wave >> 1, wc = wave & 1;
    const int lrow = lane & 15, kq = (lane >> 4) * 8;
    const int cr = (lane >> 4) * 4;
    const int r0 = t >> 2, c0 = (t & 3) * 8;

    f32x4 acc[4][4];
    #pragma unroll
    for (int i = 0; i < 4; ++i)
        #pragma unroll
        for (int j = 0; j < 4; ++j)
            acc[i][j] = (f32x4){0.f, 0.f, 0.f, 0.f};

    // ---- phase 1: H = relu(A[128x576] @ W1^T + b1) ----
    for (int k0 = 0; k0 < 576; k0 += 32) {
        GLD_LDS(A + (long)(m0 + r0) * 576 + k0 + c0,      &As[t * 8]);
        GLD_LDS(A + (long)(m0 + r0 + 64) * 576 + k0 + c0, &As[(t + 256) * 8]);
        GLD_LDS(W1 + (long)r0 * 576 + k0 + c0,            &Bs[t * 8]);
        GLD_LDS(W1 + (long)(r0 + 64) * 576 + k0 + c0,     &Bs[(t + 256) * 8]);
        __syncthreads();
        short8 af[4], bf[4];
        #pragma unroll
        for (int i = 0; i < 4; ++i)
            af[i] = *(const short8*)&As[(wr * 64 + i * 16 + lrow) * 32 + kq];
        #pragma unroll
        for (int j = 0; j < 4; ++j)
            bf[j] = *(const short8*)&Bs[(wc * 64 + j * 16 + lrow) * 32 + kq];
        #pragma unroll
        for (int i = 0; i < 4; ++i)
            #pragma unroll
            for (int j = 0; j < 4; ++j)
                acc[i][j] = __builtin_amdgcn_mfma_f32_16x16x32_bf16(af[i], bf[j], acc[i][j], 0, 0, 0);
        __syncthreads();
    }

    // park H (bias+relu, bf16) in LDS; rows = c_local, cols = k hidden
    #pragma unroll
    for (int j = 0; j < 4; ++j) {
        int col = wc * 64 + j * 16 + lrow;
        if (col < 96) {
            float bv = b1[col];
            #pragma unroll
            for (int i = 0; i < 4; ++i) {
                int row = wr * 64 + i * 16 + cr;
                #pragma unroll
                for (int r = 0; r < 4; ++r)
                    Hs[(row + r) * 104 + col] = f2bu(fmaxf(acc[i][j][r] + bv, 0.f));
            }
        }
    }
    __syncthreads();

    // ---- phase 2: G-chunk = Mp @ H^T  (m=h from Mp, n=c from Hs, K=96) ----
    f32x4 gacc[4][4];
    #pragma unroll
    for (int i = 0; i < 4; ++i)
        #pragma unroll
        for (int j = 0; j < 4; ++j)
            gacc[i][j] = (f32x4){0.f, 0.f, 0.f, 0.f};

    for (int k0 = 0; k0 < 96; k0 += 32) {
        GLD_LDS(Mp + (long)r0 * 96 + k0 + c0,        &As[t * 8]);
        GLD_LDS(Mp + (long)(r0 + 64) * 96 + k0 + c0, &As[(t + 256) * 8]);
        __syncthreads();
        short8 af[4], bf[4];
        #pragma unroll
        for (int i = 0; i < 4; ++i)
            af[i] = *(const short8*)&As[(wr * 64 + i * 16 + lrow) * 32 + kq];
        #pragma unroll
        for (int j = 0; j < 4; ++j)
            bf[j] = *(const short8*)&Hs[(wc * 64 + j * 16 + lrow) * 104 + k0 + kq];
        #pragma unroll
        for (int i = 0; i < 4; ++i)
            #pragma unroll
            for (int j = 0; j < 4; ++j)
                gacc[i][j] = __builtin_amdgcn_mfma_f32_16x16x32_bf16(af[i], bf[j], gacc[i][j], 0, 0, 0);
        __syncthreads();
    }

    const int z = m0 >> 9, m_local = m0 & 511;
    unsigned short* Gz = G + (long)z * 128 * 512;

    // store G chunk: rows h (0..127), cols c (m_local..m_local+127)
    #pragma unroll
    for (int j = 0; j < 4; ++j) {
        int cn = wc * 64 + j * 16 + lrow;
        #pragma unroll
        for (int i = 0; i < 4; ++i) {
            int h = wr * 64 + i * 16 + cr;
            #pragma unroll
            for (int r = 0; r < 4; ++r)
                Gz[(long)(h + r) * 512 + m_local + cn] = f2bu(gacc[i][j][r]);
        }
    }

    // xm: row 72 = wr*64 + i*16 + cr + r with wr=1, i=0, cr=8, r=0 (f32, exclusive)
    if (wr == 1 && cr == 8) {
        #pragma unroll
        for (int j = 0; j < 4; ++j)
            xm_raw[(long)z * 512 + m_local + wc * 64 + j * 16 + lrow] = gacc[0][j][0];
    }
}

// ---- denom: normalized means + softmax denominators ------------------------
__global__ void denom_k(const float* __restrict__ xm_raw, const float* __restrict__ b_in2,
                        float* __restrict__ xmn, float* __restrict__ invd)
{
    __shared__ float sx[512];
    __shared__ float red[256];
    int z = blockIdx.x;                              // (b,blk) 0..127
    int t = threadIdx.x;
    float p = 0.f;
    for (int i = t; i < 576; i += 256) p += b_in2[i];
    red[t] = p; __syncthreads();
    for (int o = 128; o; o >>= 1) { if (t < o) red[t] += red[t + o]; __syncthreads(); }
    float btot = red[0];
    for (int i = t; i < 512; i += 256) {
        float m = (xm_raw[(long)z * 512 + i] + btot) * (1.f / 576.f);
        sx[i] = m;
        xmn[(long)z * 512 + i] = m;
    }
    __syncthreads();
    #pragma unroll
    for (int dd = 0; dd < 2; ++dd) {
        int d = t + dd * 256;
        float xd = sx[d], s = 0.f;
        for (int c = 0; c < 512; ++c) { float df = sx[c] - xd; s += __expf(-df * df); }
        invd[(long)z * 512 + d] = 1.f / s;
    }
}

// ---- fused attention + MLP2 ------------------------------------------------
// Per block (z, d-tile of 128):
//   phase1: H2[128 d][96 h] = relu(At @ G[z]^T + b1G) -> LDS Hs
//           At[d,c] = exp(-(xmn_c-xmn_d)^2)*invd[d], built on the fly.
//   phase2: out3[(z,d)][s] = H2 @ w2op^T + b_out2, + BN column stats.
__global__ __launch_bounds__(256) void fused_attn_mlp2(
    const unsigned short* __restrict__ G,      // [128][128][512]
    const float* __restrict__ xmn, const float* __restrict__ invd,
    const float* __restrict__ b1,              // b1G [128]
    const unsigned short* __restrict__ W2,     // w2op [640][96]
    const float* __restrict__ b2,              // b_out2 [576]
    __hip_bfloat16* __restrict__ C,            // out3 [65536][576]
    float* __restrict__ statsR)                // [8][1152]
{
    __shared__ __align__(16) unsigned short smem[4096 + 4096 + 13312];
    unsigned short* As = smem;                 // [128][32] At tile
    unsigned short* Bs = smem + 4096;          // [128][32]
    unsigned short* Hs = smem + 8192;          // [128 d][104 h]
    __shared__ float sxm[512];
    __shared__ float sinv[128];

    // XCD swizzle: 4 d-tiles of one z -> same XCD (512 % 8 == 0, bijective)
    int bid = blockIdx.x;
    int lb = (bid & 7) * 64 + (bid >> 3);
    int z = lb >> 2;
    const int m0 = (lb & 3) * 128;
    const int t = threadIdx.x;
    const int lane = t & 63, wave = t >> 6;
    const int wr = wave >> 1, wc = wave & 1;
    const int lrow = lane & 15, kq = (lane >> 4) * 8;
    const int cr = (lane >> 4) * 4;
    const int r0 = t >> 2, c0 = (t & 3) * 8;
    const unsigned short* Gz = G + (long)z * 128 * 512;

    for (int i = t; i < 512; i += 256) sxm[i] = xmn[(long)z * 512 + i];
    if (t < 128) sinv[t] = invd[(long)z * 512 + m0 + t];
    __syncthreads();

    const int dA = t >> 1, cbA = (t & 1) * 16;
    const float xd = sxm[m0 + dA];
    const float ivd = sinv[dA];

    f32x4 acc[4][4];
    #pragma unroll
    for (int i = 0; i < 4; ++i)
        #pragma unroll
        for (int j = 0; j < 4; ++j)
            acc[i][j] = (f32x4){0.f, 0.f, 0.f, 0.f};

    // ---- phase 1: H2 = At @ G^T  (m=d, n=h, k=c) ----
    for (int k0 = 0; k0 < 512; k0 += 32) {
        GLD_LDS(Gz + (long)r0 * 512 + k0 + c0,        &Bs[t * 8]);
        GLD_LDS(Gz + (long)(r0 + 64) * 512 + k0 + c0, &Bs[(t + 256) * 8]);
        short8 pk0, pk1;
        #pragma unroll
        for (int e = 0; e < 8; ++e) {
            float d0 = sxm[k0 + cbA + e] - xd;
            pk0[e] = (short)f2bu(__expf(-d0 * d0) * ivd);
            float d1 = sxm[k0 + cbA + 8 + e] - xd;
            pk1[e] = (short)f2bu(__expf(-d1 * d1) * ivd);
        }
        *(short8*)&As[dA * 32 + cbA]     = pk0;
        *(short8*)&As[dA * 32 + cbA + 8] = pk1;
        __syncthreads();
        short8 af[4], bf[4];
        #pragma unroll
        for (int i = 0; i < 4; ++i)
            af[i] = *(const short8*)&As[(wr * 64 + i * 16 + lrow) * 32 + kq];
        #pragma unroll
        for (int j = 0; j < 4; ++j)
            bf[j] = *(const short8*)&Bs[(wc * 64 + j * 16 + lrow) * 32 + kq];
        #pragma unroll
        for (int i = 0; i < 4; ++i)
            #pragma unroll
            for (int j = 0; j < 4; ++j)
                acc[i][j] = __builtin_amdgcn_mfma_f32_16x16x32_bf16(af[i], bf[j], acc[i][j], 0, 0, 0);
        __syncthreads();
    }

    // park H2 = relu(acc + b1G[h]) in Hs [d][104]
    #pragma unroll
    for (int j = 0; j < 4; ++j) {
        int col = wc * 64 + j * 16 + lrow;
        if (col < 96) {
            float bv = b1[col];
            #pragma unroll
            for (int i = 0; i < 4; ++i) {
                int row = wr * 64 + i * 16 + cr;
                #pragma unroll
                for (int r = 0; r < 4; ++r)
                    Hs[(row + r) * 104 + col] = f2bu(fmaxf(acc[i][j][r] + bv, 0.f));
            }
        }
    }
    __syncthreads();

    // ---- phase 2: out3 = H2 @ w2op^T + b2, BN stats ----
    const long mg = (long)z * 512 + m0;
    float* st = statsR + (bid & 7) * 1152;
    for (int n0 = 0; n0 < 640; n0 += 128) {
        f32x4 a2[4][4];
        #pragma unroll
        for (int i = 0; i < 4; ++i)
            #pragma unroll
            for (int j = 0; j < 4; ++j)
                a2[i][j] = (f32x4){0.f, 0.f, 0.f, 0.f};

        for (int k0 = 0; k0 < 96; k0 += 32) {
            GLD_LDS(W2 + (long)(n0 + r0) * 96 + k0 + c0,      &Bs[t * 8]);
            GLD_LDS(W2 + (long)(n0 + r0 + 64) * 96 + k0 + c0, &Bs[(t + 256) * 8]);
            __syncthreads();
            short8 af[4], bf[4];
            #pragma unroll
            for (int i = 0; i < 4; ++i)
                af[i] = *(const short8*)&Hs[(wr * 64 + i * 16 + lrow) * 104 + k0 + kq];
            #pragma unroll
            for (int j = 0; j < 4; ++j)
                bf[j] = *(const short8*)&Bs[(wc * 64 + j * 16 + lrow) * 32 + kq];
            #pragma unroll
            for (int i = 0; i < 4; ++i)
                #pragma unroll
                for (int j = 0; j < 4; ++j)
                    a2[i][j] = __builtin_amdgcn_mfma_f32_16x16x32_bf16(af[i], bf[j], a2[i][j], 0, 0, 0);
            __syncthreads();
        }

        #pragma unroll
        for (int j = 0; j < 4; ++j) {
            int col = n0 + wc * 64 + j * 16 + lrow;
            bool live = col < 576;
            float bv = live ? b2[col] : 0.f;
            float s1 = 0.f, s2 = 0.f;
            #pragma unroll
            for (int i = 0; i < 4; ++i) {
                long rowb = (mg + wr * 64 + i * 16 + cr) * 576;
                #pragma unroll
                for (int r = 0; r < 4; ++r) {
                    float v = a2[i][j][r] + bv;
                    s1 += v; s2 += v * v;
                    if (live) C[rowb + (long)r * 576 + col] = __float2bfloat16(v);
                }
            }
            s1 += __shfl_xor(s1, 16, 64); s1 += __shfl_xor(s1, 32, 64);
            s2 += __shfl_xor(s2, 16, 64); s2 += __shfl_xor(s2, 32, 64);
            if ((lane >> 4) == 0 && live) {
                atomicAdd(&st[col], s1);
                atomicAdd(&st[576 + col], s2);
            }
        }
    }
}

// ---- fold BN stats into per-s scale/shift ----------------------------------
__global__ void bnfin_k(const float* __restrict__ statsR,
                        const float* __restrict__ gamma, const float* __restrict__ beta,
                        float* __restrict__ ab)
{
    int s = threadIdx.x;                             // 0..575
    float sum = 0.f, sq = 0.f;
    #pragma unroll
    for (int r = 0; r < 8; ++r) {
        sum += statsR[r * 1152 + s];
        sq  += statsR[r * 1152 + 576 + s];
    }
    float mu = sum * (1.f / 65536.f);
    float var = sq * (1.f / 65536.f) - mu * mu;
    float a = gamma[s] * rsqrtf(var + EPS);
    ab[s] = a;
    ab[576 + s] = beta[s] - mu * a;
}

// ---- epilogue: out = relu(x + 0.25 * (out3*a[s] + b[s])), float4 -----------
__global__ void final_k(const float4v* __restrict__ x4, const __hip_bfloat16* __restrict__ out3,
                        const float* __restrict__ ab, float4v* __restrict__ out4)
{
    int i = blockIdx.x * 256 + threadIdx.x;          // 0 .. 9,437,183
    int xx4 = i % 12; int t = i / 12;
    int y = t % 48; t /= 48;
    int c = t & 1023; int n = t >> 10;
    int xx = xx4 * 4;
    int ti = (y / 24) * 2 + (xx / 24);
    int b = ti * 16 + n;
    int s = (y % 24) * 24 + (xx % 24);
    const __hip_bfloat16* o3 = out3 + (((long)b << 10) + c) * 576 + s;
    float4v xv = x4[i];
    float4v o;
    #pragma unroll
    for (int e = 0; e < 4; ++e) {
        float v = __bfloat162float(o3[e]);
        float bn = v * ab[s + e] + ab[576 + s + e];
        float r = (e == 0 ? xv.x : e == 1 ? xv.y : e == 2 ? xv.z : xv.w) + 0.25f * bn;
        if (e == 0) o.x = fmaxf(r, 0.f);
        else if (e == 1) o.y = fmaxf(r, 0.f);
        else if (e == 2) o.z = fmaxf(r, 0.f);
        else o.w = fmaxf(r, 0.f);
    }
    out4[i] = o;
}

extern "C" void kernel_launch(void* const* d_in, const int* in_sizes, int n_in,
                              void* d_out, int out_size, void* d_ws, size_t ws_size,
                              hipStream_t stream)
{
    const float* x      = (const float*)d_in[0];
    const float* w_in1  = (const float*)d_in[1];
    const float* b_in1  = (const float*)d_in[2];
    const float* w_in2  = (const float*)d_in[3];
    const float* b_in2  = (const float*)d_in[4];
    const float* w_out1 = (const float*)d_in[5];
    const float* b_out1 = (const float*)d_in[6];
    const float* w_out2 = (const float*)d_in[7];
    const float* b_out2 = (const float*)d_in[8];
    const float* gamma  = (const float*)d_in[9];
    const float* beta   = (const float*)d_in[10];

    char* ws = (char*)d_ws;
    __hip_bfloat16* xv0    = (__hip_bfloat16*)(ws);                 // 75,497,472
    __hip_bfloat16* out3   = (__hip_bfloat16*)(ws + 75497472L);     // 75,497,472
    unsigned short* G      = (unsigned short*)(ws + 150994944L);    // 16,777,216
    float*          xmn    = (float*)(ws + 167772160L);             // 262,144
    float*          xm_raw = (float*)(ws + 168034304L);             // 262,144
    float*          invd   = (float*)(ws + 168296448L);             // 262,144
    float*          statsR = (float*)(ws + 168558592L);             // 36,864
    float*          ab     = (float*)(ws + 168595456L);             // 4,608
    __hip_bfloat16* w1p    = (__hip_bfloat16*)(ws + 168600064L);    // 147,456
    __hip_bfloat16* w2op   = (__hip_bfloat16*)(ws + 168747520L);    // 122,880
    float*          b1p    = (float*)(ws + 168870400L);             // 512
    __hip_bfloat16* Mp     = (__hip_bfloat16*)(ws + 168870912L);    // 24,576
    float*          b1G    = (float*)(ws + 168895488L);             // 512

    hipMemsetAsync(statsR, 0, 36864, stream);

    prep_k<<<288, 256, 0, stream>>>(w_in1, b_in1, w_in2, w_out2, w1p, w2op, b1p);
    prepM_k<<<48, 256, 0, stream>>>(w_out1, w_in2, b_in2, b_out1, Mp, b1G);

    extract_k<<<36864, 256, 0, stream>>>((const float4v*)x, xv0);

    // fused MLP1 -> G (xv1 never materialized); xm from row-72 fragment
    fused_mlp1<<<512, 256, 0, stream>>>(
        (const unsigned short*)xv0, (const unsigned short*)w1p, b1p,
        (const unsigned short*)Mp, G, xm_raw);

    denom_k<<<128, 256, 0, stream>>>(xm_raw, b_in2, xmn, invd);

    // fused attention + MLP2: H2 = relu(At@G^T + b1G), out3 = H2@w2op^T + BN stats
    fused_attn_mlp2<<<512, 256, 0, stream>>>(
        G, xmn, invd, b1G, (const unsigned short*)w2op, b_out2,
        out3, statsR);

    bnfin_k<<<1, 576, 0, stream>>>(statsR, gamma, beta, ab);

    final_k<<<36864, 256, 0, stream>>>((const float4v*)x, out3, ab, (float4v*)d_out);
}

// Round 5
// 451.854 us; speedup vs baseline: 1.2780x; 1.0728x over previous
//
#include <hip/hip_runtime.h>
#include <hip/hip_bf16.h>

// ============================================================================
// CrossNeuronBlock — round 7: extract fused into MLP1 + LDS aliasing.
//   fused_mlp1 now reads x directly (f32->bf16 in-register during A-staging,
//   BK=96 = 4 spatial rows of the 24x24 tile, fully float4-aligned). xv0 and
//   extract_k are gone (-151 MB round trip, -1 dispatch). Phase-1: 2 barriers
//   per 96-K stage (was 6), A/B in padded [128][104] LDS (conflict-free).
//   H parks into the A-staging buffer (alias, written from regs post-barrier):
//   fused_mlp1 LDS 53.2 KB, fused_attn_mlp2 37.4 KB -> 4 blocks/CU (was 3).
//   Pipeline: fused_mlp1 -> denom_k -> fused_attn_mlp2 -> bnfin -> final.
// ============================================================================

#define EPS 1e-5f

typedef __attribute__((ext_vector_type(8))) short short8;
typedef __attribute__((ext_vector_type(4))) short short4v;
typedef __attribute__((ext_vector_type(4))) float f32x4;
typedef __attribute__((ext_vector_type(4))) float float4v;

#define GLD_LDS(g, l) __builtin_amdgcn_global_load_lds( \
    (const __attribute__((address_space(1))) void*)(g), \
    (__attribute__((address_space(3))) void*)(l), 16, 0, 0)

static __device__ __forceinline__ unsigned short f2bu(float f) {
    union { __hip_bfloat16 h; unsigned short u; } cv;
    cv.h = __float2bfloat16(f);
    return cv.u;
}

// ---- weight/bias prep: bf16 + zero-padding ---------------------------------
__global__ void prep_k(const float* __restrict__ w_in1, const float* __restrict__ b_in1,
                       const float* __restrict__ w_in2, const float* __restrict__ w_out2,
                       __hip_bfloat16* __restrict__ w1p, __hip_bfloat16* __restrict__ w2op,
                       float* __restrict__ b1p)
{
    int i = blockIdx.x * 256 + threadIdx.x;          // 0 .. 73727
    if (i < 128 * 576) {
        int r = i / 576, c = i - r * 576;
        w1p[i] = __float2bfloat16(r < 72 ? w_in1[r * 576 + c] : 0.f);
    }
    if (i < 640 * 96) {
        int r = i / 96, c = i - r * 96;
        bool ok = (r < 576) && (c < 72);
        w2op[i] = __float2bfloat16(ok ? w_out2[r * 72 + c] : 0.f);
    }
    if (i < 128)
        b1p[i] = i < 72 ? b_in1[i] : 0.f;
}

// ---- prepM: Mp = w_out1 @ w_in2 (f32 accum, bf16 once); row 72 = colsum(w_in2);
//      b1G[h] = b_out1[h] + w_out1[h,:] @ b_in2 ---------------------------------
__global__ void prepM_k(const float* __restrict__ w_out1, const float* __restrict__ w_in2,
                        const float* __restrict__ b_in2, const float* __restrict__ b_out1,
                        __hip_bfloat16* __restrict__ Mp, float* __restrict__ b1G)
{
    int i = blockIdx.x * 256 + threadIdx.x;          // 0 .. 12287
    if (i >= 128 * 96) return;
    int h = i / 96, k = i - h * 96;
    float m = 0.f;
    if (h < 72 && k < 72) {
        for (int s = 0; s < 576; ++s)
            m += w_out1[h * 576 + s] * w_in2[s * 72 + k];
    } else if (h == 72 && k < 72) {
        for (int s = 0; s < 576; ++s)
            m += w_in2[s * 72 + k];
    }
    Mp[i] = __float2bfloat16(m);
    if (k == 0) {
        float c = 0.f;
        if (h < 72)
            for (int s = 0; s < 576; ++s)
                c += w_out1[h * 576 + s] * b_in2[s];
        b1G[h] = (h < 72) ? b_out1[h] + c : 0.f;
    }
}

// ---- fused MLP1 -> G (reads x directly) ------------------------------------
// Per block (128 rows m = (z, c_local chunk)):
//   phase1: H[128 c][96 k] = relu(bf16(x-tile)@W1^T + b1), BK=96 (4 spatial
//           rows), A reg-staged f32->bf16, W1 reg-staged; LDS [128][104].
//   park:   H -> As alias.
//   phase2: G-chunk[128 h][128 c] = Mp @ H^T (K=96); row 72 = xm (f32).
__global__ __launch_bounds__(256) void fused_mlp1(
    const float* __restrict__ x,               // [16][1024][48][48]
    const unsigned short* __restrict__ W1,     // w1p [128][576]
    const float* __restrict__ b1,              // b1p [128]
    const unsigned short* __restrict__ Mp,     // [128][96]
    unsigned short* __restrict__ G,            // [128 z][128 h][512 c]
    float* __restrict__ xm_raw)                // [128][512]
{
    __shared__ __align__(16) unsigned short smem[13312 + 13312];
    unsigned short* As = smem;                 // [128][104]; phase2: Hs alias
    unsigned short* Bs = smem + 13312;         // [128][104]; phase2: Mp [128][32]

    const int m0 = blockIdx.x * 128;
    const int t = threadIdx.x;
    const int lane = t & 63, wave = t >> 6;
    const int wr = wave >> 1, wc = wave & 1;
    const int lrow = lane & 15, kq = (lane >> 4) * 8;
    const int cr = (lane >> 4) * 4;
    const int r0 = t >> 2, c0 = (t & 3) * 8;

    // staging coords: 2 threads per row; hf selects x-row pair within stage
    const int rr = t >> 1, hf = t & 1;
    {
        // nothing
    }
    const int Mrow = m0 + rr;
    const int cch = Mrow & 1023, bb = Mrow >> 10;
    const int nb = bb & 15, ti = bb >> 4;
    const int ty = (ti >> 1) * 24, tx = (ti & 1) * 24;
    const float* xrow = x + (((long)((nb << 10) + cch) * 48 + ty) * 48 + tx);
    const unsigned short* w1row = W1 + rr * 576 + hf * 48;

    f32x4 acc[4][4];
    #pragma unroll
    for (int i = 0; i < 4; ++i)
        #pragma unroll
        for (int j = 0; j < 4; ++j)
            acc[i][j] = (f32x4){0.f, 0.f, 0.f, 0.f};

    // ---- phase 1: 6 stages of BK=96 ----
    for (int ks = 0; ks < 6; ++ks) {
        __syncthreads();                       // prev stage's reads done
        // A: x gather + f32->bf16; rows rr, x-rows (hf*2+q), 6 float4 each
        #pragma unroll
        for (int q = 0; q < 2; ++q) {
            const int sy = ks * 4 + hf * 2 + q;
            #pragma unroll
            for (int xx = 0; xx < 6; ++xx) {
                float4v v = *(const float4v*)(xrow + sy * 48 + xx * 4);
                short4v pk;
                pk.x = (short)f2bu(v.x); pk.y = (short)f2bu(v.y);
                pk.z = (short)f2bu(v.z); pk.w = (short)f2bu(v.w);
                *(short4v*)&As[rr * 104 + (hf * 2 + q) * 24 + xx * 4] = pk;
            }
        }
        // B: W1 cols ks*96 + hf*48 + [0,48)
        #pragma unroll
        for (int sg = 0; sg < 6; ++sg) {
            short8 w = *(const short8*)(w1row + ks * 96 + sg * 8);
            *(short8*)&Bs[rr * 104 + hf * 48 + sg * 8] = w;
        }
        __syncthreads();
        #pragma unroll
        for (int kk = 0; kk < 3; ++kk) {
            short8 af[4], bf[4];
            #pragma unroll
            for (int i = 0; i < 4; ++i)
                af[i] = *(const short8*)&As[(wr * 64 + i * 16 + lrow) * 104 + kk * 32 + kq];
            #pragma unroll
            for (int j = 0; j < 4; ++j)
                bf[j] = *(const short8*)&Bs[(wc * 64 + j * 16 + lrow) * 104 + kk * 32 + kq];
            #pragma unroll
            for (int i = 0; i < 4; ++i)
                #pragma unroll
                for (int j = 0; j < 4; ++j)
                    acc[i][j] = __builtin_amdgcn_mfma_f32_16x16x32_bf16(af[i], bf[j], acc[i][j], 0, 0, 0);
        }
    }
    __syncthreads();                           // last MFMA reads done

    // park H (bias+relu, bf16) into As alias [128 c][104 k]
    #pragma unroll
    for (int j = 0; j < 4; ++j) {
        int col = wc * 64 + j * 16 + lrow;
        if (col < 96) {
            float bv = b1[col];
            #pragma unroll
            for (int i = 0; i < 4; ++i) {
                int row = wr * 64 + i * 16 + cr;
                #pragma unroll
                for (int r = 0; r < 4; ++r)
                    As[(row + r) * 104 + col] = f2bu(fmaxf(acc[i][j][r] + bv, 0.f));
            }
        }
    }
    __syncthreads();

    // ---- phase 2: G-chunk = Mp @ H^T  (m=h from Mp in Bs, n=c from As, K=96)
    f32x4 gacc[4][4];
    #pragma unroll
    for (int i = 0; i < 4; ++i)
        #pragma unroll
        for (int j = 0; j < 4; ++j)
            gacc[i][j] = (f32x4){0.f, 0.f, 0.f, 0.f};

    for (int k0 = 0; k0 < 96; k0 += 32) {
        GLD_LDS(Mp + (long)r0 * 96 + k0 + c0,        &Bs[t * 8]);
        GLD_LDS(Mp + (long)(r0 + 64) * 96 + k0 + c0, &Bs[(t + 256) * 8]);
        __syncthreads();
        short8 af[4], bf[4];
        #pragma unroll
        for (int i = 0; i < 4; ++i)
            af[i] = *(const short8*)&Bs[(wr * 64 + i * 16 + lrow) * 32 + kq];
        #pragma unroll
        for (int j = 0; j < 4; ++j)
            bf[j] = *(const short8*)&As[(wc * 64 + j * 16 + lrow) * 104 + k0 + kq];
        #pragma unroll
        for (int i = 0; i < 4; ++i)
            #pragma unroll
            for (int j = 0; j < 4; ++j)
                gacc[i][j] = __builtin_amdgcn_mfma_f32_16x16x32_bf16(af[i], bf[j], gacc[i][j], 0, 0, 0);
        __syncthreads();
    }

    const int z = m0 >> 9, m_local = m0 & 511;
    unsigned short* Gz = G + (long)z * 128 * 512;

    // store G chunk: rows h (0..127), cols c (m_local..m_local+127)
    #pragma unroll
    for (int j = 0; j < 4; ++j) {
        int cn = wc * 64 + j * 16 + lrow;
        #pragma unroll
        for (int i = 0; i < 4; ++i) {
            int h = wr * 64 + i * 16 + cr;
            #pragma unroll
            for (int r = 0; r < 4; ++r)
                Gz[(long)(h + r) * 512 + m_local + cn] = f2bu(gacc[i][j][r]);
        }
    }

    // xm: row 72 = wr*64 + i*16 + cr + r with wr=1, i=0, cr=8, r=0 (f32, exclusive)
    if (wr == 1 && cr == 8) {
        #pragma unroll
        for (int j = 0; j < 4; ++j)
            xm_raw[(long)z * 512 + m_local + wc * 64 + j * 16 + lrow] = gacc[0][j][0];
    }
}

// ---- denom: normalized means + softmax denominators ------------------------
__global__ void denom_k(const float* __restrict__ xm_raw, const float* __restrict__ b_in2,
                        float* __restrict__ xmn, float* __restrict__ invd)
{
    __shared__ float sx[512];
    __shared__ float red[256];
    int z = blockIdx.x;                              // (b,blk) 0..127
    int t = threadIdx.x;
    float p = 0.f;
    for (int i = t; i < 576; i += 256) p += b_in2[i];
    red[t] = p; __syncthreads();
    for (int o = 128; o; o >>= 1) { if (t < o) red[t] += red[t + o]; __syncthreads(); }
    float btot = red[0];
    for (int i = t; i < 512; i += 256) {
        float m = (xm_raw[(long)z * 512 + i] + btot) * (1.f / 576.f);
        sx[i] = m;
        xmn[(long)z * 512 + i] = m;
    }
    __syncthreads();
    #pragma unroll
    for (int dd = 0; dd < 2; ++dd) {
        int d = t + dd * 256;
        float xd = sx[d], s = 0.f;
        for (int c = 0; c < 512; ++c) { float df = sx[c] - xd; s += __expf(-df * df); }
        invd[(long)z * 512 + d] = 1.f / s;
    }
}

// ---- fused attention + MLP2 ------------------------------------------------
// Per block (z, d-tile of 128):
//   phase1: H2[128 d][96 h] = relu(At @ G[z]^T + b1G); At on the fly.
//   park:   H2 -> smem base alias [128][104].
//   phase2: out3[(z,d)][s] = H2 @ w2op^T + b_out2, + BN column stats.
__global__ __launch_bounds__(256) void fused_attn_mlp2(
    const unsigned short* __restrict__ G,      // [128][128][512]
    const float* __restrict__ xmn, const float* __restrict__ invd,
    const float* __restrict__ b1,              // b1G [128]
    const unsigned short* __restrict__ W2,     // w2op [640][96]
    const float* __restrict__ b2,              // b_out2 [576]
    __hip_bfloat16* __restrict__ C,            // out3 [65536][576]
    float* __restrict__ statsR)                // [8][1152]
{
    __shared__ __align__(16) unsigned short smem[17408];
    unsigned short* As = smem;                 // phase1: [128][32] At tile
    unsigned short* Bs = smem + 4096;          // phase1: [128][32] G staging
    unsigned short* Hs = smem;                 // phase2: [128 d][104 h] (alias)
    unsigned short* Ws = smem + 13312;         // phase2: [128][32] W2 staging
    __shared__ float sxm[512];
    __shared__ float sinv[128];

    // XCD swizzle: 4 d-tiles of one z -> same XCD (512 % 8 == 0, bijective)
    int bid = blockIdx.x;
    int lb = (bid & 7) * 64 + (bid >> 3);
    int z = lb >> 2;
    const int m0 = (lb & 3) * 128;
    const int t = threadIdx.x;
    const int lane = t & 63, wave = t >> 6;
    const int wr = wave >> 1, wc = wave & 1;
    const int lrow = lane & 15, kq = (lane >> 4) * 8;
    const int cr = (lane >> 4) * 4;
    const int r0 = t >> 2, c0 = (t & 3) * 8;
    const unsigned short* Gz = G + (long)z * 128 * 512;

    for (int i = t; i < 512; i += 256) sxm[i] = xmn[(long)z * 512 + i];
    if (t < 128) sinv[t] = invd[(long)z * 512 + m0 + t];
    __syncthreads();

    const int dA = t >> 1, cbA = (t & 1) * 16;
    const float xd = sxm[m0 + dA];
    const float ivd = sinv[dA];

    f32x4 acc[4][4];
    #pragma unroll
    for (int i = 0; i < 4; ++i)
        #pragma unroll
        for (int j = 0; j < 4; ++j)
            acc[i][j] = (f32x4){0.f, 0.f, 0.f, 0.f};

    // ---- phase 1: H2 = At @ G^T  (m=d, n=h, k=c) ----
    for (int k0 = 0; k0 < 512; k0 += 32) {
        GLD_LDS(Gz + (long)r0 * 512 + k0 + c0,        &Bs[t * 8]);
        GLD_LDS(Gz + (long)(r0 + 64) * 512 + k0 + c0, &Bs[(t + 256) * 8]);
        short8 pk0, pk1;
        #pragma unroll
        for (int e = 0; e < 8; ++e) {
            float d0 = sxm[k0 + cbA + e] - xd;
            pk0[e] = (short)f2bu(__expf(-d0 * d0) * ivd);
            float d1 = sxm[k0 + cbA + 8 + e] - xd;
            pk1[e] = (short)f2bu(__expf(-d1 * d1) * ivd);
        }
        *(short8*)&As[dA * 32 + cbA]     = pk0;
        *(short8*)&As[dA * 32 + cbA + 8] = pk1;
        __syncthreads();
        short8 af[4], bf[4];
        #pragma unroll
        for (int i = 0; i < 4; ++i)
            af[i] = *(const short8*)&As[(wr * 64 + i * 16 + lrow) * 32 + kq];
        #pragma unroll
        for (int j = 0; j < 4; ++j)
            bf[j] = *(const short8*)&Bs[(wc * 64 + j * 16 + lrow) * 32 + kq];
        #pragma unroll
        for (int i = 0; i < 4; ++i)
            #pragma unroll
            for (int j = 0; j < 4; ++j)
                acc[i][j] = __builtin_amdgcn_mfma_f32_16x16x32_bf16(af[i], bf[j], acc[i][j], 0, 0, 0);
        __syncthreads();
    }

    // park H2 = relu(acc + b1G[h]) into Hs alias [d][104]
    #pragma unroll
    for (int j = 0; j < 4; ++j) {
        int col = wc * 64 + j * 16 + lrow;
        if (col < 96) {
            float bv = b1[col];
            #pragma unroll
            for (int i = 0; i < 4; ++i) {
                int row = wr * 64 + i * 16 + cr;
                #pragma unroll
                for (int r = 0; r < 4; ++r)
                    Hs[(row + r) * 104 + col] = f2bu(fmaxf(acc[i][j][r] + bv, 0.f));
            }
        }
    }
    __syncthreads();

    // ---- phase 2: out3 = H2 @ w2op^T + b2, BN stats ----
    const long mg = (long)z * 512 + m0;
    float* st = statsR + (bid & 7) * 1152;
    for (int n0 = 0; n0 < 640; n0 += 128) {
        f32x4 a2[4][4];
        #pragma unroll
        for (int i = 0; i < 4; ++i)
            #pragma unroll
            for (int j = 0; j < 4; ++j)
                a2[i][j] = (f32x4){0.f, 0.f, 0.f, 0.f};

        for (int k0 = 0; k0 < 96; k0 += 32) {
            GLD_LDS(W2 + (long)(n0 + r0) * 96 + k0 + c0,      &Ws[t * 8]);
            GLD_LDS(W2 + (long)(n0 + r0 + 64) * 96 + k0 + c0, &Ws[(t + 256) * 8]);
            __syncthreads();
            short8 af[4], bf[4];
            #pragma unroll
            for (int i = 0; i < 4; ++i)
                af[i] = *(const short8*)&Hs[(wr * 64 + i * 16 + lrow) * 104 + k0 + kq];
            #pragma unroll
            for (int j = 0; j < 4; ++j)
                bf[j] = *(const short8*)&Ws[(wc * 64 + j * 16 + lrow) * 32 + kq];
            #pragma unroll
            for (int i = 0; i < 4; ++i)
                #pragma unroll
                for (int j = 0; j < 4; ++j)
                    a2[i][j] = __builtin_amdgcn_mfma_f32_16x16x32_bf16(af[i], bf[j], a2[i][j], 0, 0, 0);
            __syncthreads();
        }

        #pragma unroll
        for (int j = 0; j < 4; ++j) {
            int col = n0 + wc * 64 + j * 16 + lrow;
            bool live = col < 576;
            float bv = live ? b2[col] : 0.f;
            float s1 = 0.f, s2 = 0.f;
            #pragma unroll
            for (int i = 0; i < 4; ++i) {
                long rowb = (mg + wr * 64 + i * 16 + cr) * 576;
                #pragma unroll
                for (int r = 0; r < 4; ++r) {
                    float v = a2[i][j][r] + bv;
                    s1 += v; s2 += v * v;
                    if (live) C[rowb + (long)r * 576 + col] = __float2bfloat16(v);
                }
            }
            s1 += __shfl_xor(s1, 16, 64); s1 += __shfl_xor(s1, 32, 64);
            s2 += __shfl_xor(s2, 16, 64); s2 += __shfl_xor(s2, 32, 64);
            if ((lane >> 4) == 0 && live) {
                atomicAdd(&st[col], s1);
                atomicAdd(&st[576 + col], s2);
            }
        }
    }
}

// ---- fold BN stats into per-s scale/shift ----------------------------------
__global__ void bnfin_k(const float* __restrict__ statsR,
                        const float* __restrict__ gamma, const float* __restrict__ beta,
                        float* __restrict__ ab)
{
    int s = threadIdx.x;                             // 0..575
    float sum = 0.f, sq = 0.f;
    #pragma unroll
    for (int r = 0; r < 8; ++r) {
        sum += statsR[r * 1152 + s];
        sq  += statsR[r * 1152 + 576 + s];
    }
    float mu = sum * (1.f / 65536.f);
    float var = sq * (1.f / 65536.f) - mu * mu;
    float a = gamma[s] * rsqrtf(var + EPS);
    ab[s] = a;
    ab[576 + s] = beta[s] - mu * a;
}

// ---- epilogue: out = relu(x + 0.25 * (out3*a[s] + b[s])), float4 -----------
__global__ void final_k(const float4v* __restrict__ x4, const __hip_bfloat16* __restrict__ out3,
                        const float* __restrict__ ab, float4v* __restrict__ out4)
{
    int i = blockIdx.x * 256 + threadIdx.x;          // 0 .. 9,437,183
    int xx4 = i % 12; int t = i / 12;
    int y = t % 48; t /= 48;
    int c = t & 1023; int n = t >> 10;
    int xx = xx4 * 4;
    int ti = (y / 24) * 2 + (xx / 24);
    int b = ti * 16 + n;
    int s = (y % 24) * 24 + (xx % 24);
    const __hip_bfloat16* o3 = out3 + (((long)b << 10) + c) * 576 + s;
    float4v xv = x4[i];
    float4v o;
    #pragma unroll
    for (int e = 0; e < 4; ++e) {
        float v = __bfloat162float(o3[e]);
        float bn = v * ab[s + e] + ab[576 + s + e];
        float r = (e == 0 ? xv.x : e == 1 ? xv.y : e == 2 ? xv.z : xv.w) + 0.25f * bn;
        if (e == 0) o.x = fmaxf(r, 0.f);
        else if (e == 1) o.y = fmaxf(r, 0.f);
        else if (e == 2) o.z = fmaxf(r, 0.f);
        else o.w = fmaxf(r, 0.f);
    }
    out4[i] = o;
}

extern "C" void kernel_launch(void* const* d_in, const int* in_sizes, int n_in,
                              void* d_out, int out_size, void* d_ws, size_t ws_size,
                              hipStream_t stream)
{
    const float* x      = (const float*)d_in[0];
    const float* w_in1  = (const float*)d_in[1];
    const float* b_in1  = (const float*)d_in[2];
    const float* w_in2  = (const float*)d_in[3];
    const float* b_in2  = (const float*)d_in[4];
    const float* w_out1 = (const float*)d_in[5];
    const float* b_out1 = (const float*)d_in[6];
    const float* w_out2 = (const float*)d_in[7];
    const float* b_out2 = (const float*)d_in[8];
    const float* gamma  = (const float*)d_in[9];
    const float* beta   = (const float*)d_in[10];

    char* ws = (char*)d_ws;
    __hip_bfloat16* out3   = (__hip_bfloat16*)(ws);                 // 75,497,472
    unsigned short* G      = (unsigned short*)(ws + 75497472L);     // 16,777,216
    float*          xmn    = (float*)(ws + 92274688L);              // 262,144
    float*          xm_raw = (float*)(ws + 92536832L);              // 262,144
    float*          invd   = (float*)(ws + 92798976L);              // 262,144
    float*          statsR = (float*)(ws + 93061120L);              // 36,864
    float*          ab     = (float*)(ws + 93097984L);              // 4,608
    __hip_bfloat16* w1p    = (__hip_bfloat16*)(ws + 93102592L);     // 147,456
    __hip_bfloat16* w2op   = (__hip_bfloat16*)(ws + 93250048L);     // 122,880
    float*          b1p    = (float*)(ws + 93372928L);              // 512
    __hip_bfloat16* Mp     = (__hip_bfloat16*)(ws + 93373440L);     // 24,576
    float*          b1G    = (float*)(ws + 93398016L);              // 512

    hipMemsetAsync(statsR, 0, 36864, stream);

    prep_k<<<288, 256, 0, stream>>>(w_in1, b_in1, w_in2, w_out2, w1p, w2op, b1p);
    prepM_k<<<48, 256, 0, stream>>>(w_out1, w_in2, b_in2, b_out1, Mp, b1G);

    // fused MLP1 -> G (reads x directly; xv0 eliminated); xm from row-72 fragment
    fused_mlp1<<<512, 256, 0, stream>>>(
        x, (const unsigned short*)w1p, b1p,
        (const unsigned short*)Mp, G, xm_raw);

    denom_k<<<128, 256, 0, stream>>>(xm_raw, b_in2, xmn, invd);

    // fused attention + MLP2: H2 = relu(At@G^T + b1G), out3 = H2@w2op^T + BN stats
    fused_attn_mlp2<<<512, 256, 0, stream>>>(
        G, xmn, invd, b1G, (const unsigned short*)w2op, b_out2,
        out3, statsR);

    bnfin_k<<<1, 576, 0, stream>>>(statsR, gamma, beta, ab);

    final_k<<<36864, 256, 0, stream>>>((const float4v*)x, out3, ab, (float4v*)d_out);
}